// Round 3
// baseline (404.898 us; speedup 1.0000x reference)
//
#include <hip/hip_runtime.h>
#include <cstdint>
#include <cstddef>

// ---------- types ----------
typedef __attribute__((ext_vector_type(8))) short short8;   // 8 bf16 = 4 VGPR
typedef __attribute__((ext_vector_type(4))) float floatx4;  // MFMA C/D

#define NTOK   4096
#define SHBASE 8192      // shared-expert segment base slot (2*NTOK)
#define NSLOT  12288     // 3*NTOK
#define MAT_ELEMS (1024 * 1024)

__device__ __forceinline__ unsigned short f2b(float f) {
  unsigned u = __float_as_uint(f);
  u = (u + 0x7fffu + ((u >> 16) & 1u)) >> 16;
  return (unsigned short)u;
}

// async global->LDS, 16B per lane. gsrc: per-lane address, ldst: wave-uniform base.
#define GLD16(gsrc, ldst)                                                              \
  __builtin_amdgcn_global_load_lds(                                                    \
      (const __attribute__((address_space(1))) unsigned int*)(gsrc),                   \
      (__attribute__((address_space(3))) unsigned int*)(ldst), 16, 0, 0)

// ---------- K0: bias from loop embedding, init counters ----------
__global__ void setup_kernel(const float* __restrict__ Wr,
                             const float* __restrict__ loopTable,
                             const int* __restrict__ loopIdx,
                             float* __restrict__ bias, int* __restrict__ cnt) {
  int t = threadIdx.x;
  if (t < 9) cnt[t] = (t == 8) ? NTOK : 0;
  if (t < 8) bias[t] = 0.0f;
  __syncthreads();
  const float* emb = loopTable + (size_t)(*loopIdx) * 1024;
  float partial[8] = {0, 0, 0, 0, 0, 0, 0, 0};
  for (int d = t; d < 1024; d += 256) {
    float ev = emb[d];
    const float* wr = Wr + (size_t)(1024 + d) * 8;
#pragma unroll
    for (int e = 0; e < 8; e++) partial[e] += ev * wr[e];
  }
#pragma unroll
  for (int off = 32; off > 0; off >>= 1)
#pragma unroll
    for (int e = 0; e < 8; e++) partial[e] += __shfl_xor(partial[e], off, 64);
  if ((t & 63) == 0)
#pragma unroll
    for (int e = 0; e < 8; e++) atomicAdd(&bias[e], partial[e]);
}

// ---------- K1: router (64 tokens/block, scalar Wr reads) + x->bf16 cast ----------
__global__ __launch_bounds__(256) void router_kernel(
    const float* __restrict__ x, const float* __restrict__ Wr,
    const float* __restrict__ bias, unsigned short* __restrict__ packedX,
    int* __restrict__ cnt, int* __restrict__ permSparse,
    float* __restrict__ wSparse, int* __restrict__ permToken,
    float* __restrict__ slotW) {
  int tid = threadIdx.x;
  int lane = tid & 63;
  int seg = __builtin_amdgcn_readfirstlane(tid >> 6);  // wave-uniform
  int tok0 = blockIdx.x << 6;
  int tok = tok0 + lane;

  __shared__ float red[4][64][9];
  __shared__ int lcnt[8];
  __shared__ int lbase[8];
  __shared__ int sE[64][2];
  __shared__ float sP[64][2];
  __shared__ int sPos[64][2];

  if (tid < 8) lcnt[tid] = 0;

  float lg[8] = {0, 0, 0, 0, 0, 0, 0, 0};
  const float* xr = x + (size_t)tok * 1024 + seg * 256;
  const float* wr = Wr + (size_t)seg * 256 * 8;  // scalar base
  for (int i = 0; i < 256; i += 4) {
    float4 xv = *(const float4*)(xr + i);
    float xs[4] = {xv.x, xv.y, xv.z, xv.w};
#pragma unroll
    for (int r = 0; r < 4; r++) {
      const float4* w4 = (const float4*)(wr + (size_t)(i + r) * 8);
      float4 wa = w4[0], wb = w4[1];
      float xv1 = xs[r];
      lg[0] += xv1 * wa.x; lg[1] += xv1 * wa.y; lg[2] += xv1 * wa.z; lg[3] += xv1 * wa.w;
      lg[4] += xv1 * wb.x; lg[5] += xv1 * wb.y; lg[6] += xv1 * wb.z; lg[7] += xv1 * wb.w;
    }
  }
#pragma unroll
  for (int e = 0; e < 8; e++) red[seg][lane][e] = lg[e];
  __syncthreads();

  if (tid < 64) {
    float l[8];
#pragma unroll
    for (int e = 0; e < 8; e++)
      l[e] = red[0][tid][e] + red[1][tid][e] + red[2][tid][e] + red[3][tid][e] + bias[e];
    int i0 = 0; float l0 = l[0];
#pragma unroll
    for (int e = 1; e < 8; e++) if (l[e] > l0) { l0 = l[e]; i0 = e; }
    int i1 = -1; float l1 = -1e30f;
#pragma unroll
    for (int e = 0; e < 8; e++) if (e != i0 && l[e] > l1) { l1 = l[e]; i1 = e; }
    float p0 = 1.0f / (1.0f + __expf(-l0));
    float p1 = 1.0f / (1.0f + __expf(-l1));
    sE[tid][0] = i0; sP[tid][0] = p0; sPos[tid][0] = atomicAdd(&lcnt[i0], 1);
    sE[tid][1] = i1; sP[tid][1] = p1; sPos[tid][1] = atomicAdd(&lcnt[i1], 1);
    int t = tok0 + tid;
    permToken[SHBASE + t] = t;
    slotW[SHBASE + t] = 1.0f;
  }
  __syncthreads();
  if (tid < 8) lbase[tid] = atomicAdd(&cnt[tid], lcnt[tid]);
  __syncthreads();
  if (tid < 64) {
    int t = tok0 + tid;
#pragma unroll
    for (int j = 0; j < 2; j++) {
      int e = sE[tid][j];
      int pos = lbase[e] + sPos[tid][j];
      permSparse[e * NTOK + pos] = t;
      wSparse[e * NTOK + pos] = sP[tid][j];
    }
  }

  // cast 64 token rows -> bf16 shared segment (coalesced)
  const float4* xs4 = (const float4*)(x + (size_t)tok0 * 1024);
  uint2* dst = (uint2*)(packedX + (size_t)(SHBASE + tok0) * 1024);
  for (int i = tid; i < 64 * 256; i += 256) {
    float4 v = xs4[i];
    uint2 pk;
    pk.x = (unsigned)f2b(v.x) | ((unsigned)f2b(v.y) << 16);
    pk.y = (unsigned)f2b(v.z) | ((unsigned)f2b(v.w) << 16);
    dst[i] = pk;
  }
}

// ---------- K2: exclusive scan of 9 counts ----------
__global__ void scan_kernel(const int* __restrict__ cnt, int* __restrict__ offs) {
  if (threadIdx.x == 0) {
    int s = 0;
    for (int e = 0; e < 9; e++) { offs[e] = s; s += cnt[e]; }
  }
}

// ---------- K3: finalize routed slot metadata (replaces row gather) ----------
__global__ __launch_bounds__(256) void finalize_kernel(
    const int* __restrict__ cnt, const int* __restrict__ offs,
    const int* __restrict__ permSparse, const float* __restrict__ wSparse,
    int* __restrict__ permToken, float* __restrict__ slotW) {
  int idx = blockIdx.x * 256 + threadIdx.x;   // 8 * NTOK total
  int e = idx >> 12, r = idx & (NTOK - 1);
  if (e < 8 && r < cnt[e]) {
    int slot = offs[e] + r;
    permToken[slot] = permSparse[e * NTOK + r];
    slotW[slot] = wSparse[e * NTOK + r];
  }
}

// ---------- K4: transpose+cast 27 weight matrices to bf16 [out][in] ----------
__global__ __launch_bounds__(256) void transpose_cast(
    const float* __restrict__ Wg, const float* __restrict__ Wu,
    const float* __restrict__ Wd, const float* __restrict__ sg,
    const float* __restrict__ su, const float* __restrict__ sd,
    unsigned short* __restrict__ Wt) {
  int m = blockIdx.z;
  int type = m / 9, e = m % 9;
  const float* src;
  if (type == 0)      src = (e < 8) ? Wg + (size_t)e * MAT_ELEMS : sg;
  else if (type == 1) src = (e < 8) ? Wu + (size_t)e * MAT_ELEMS : su;
  else                src = (e < 8) ? Wd + (size_t)e * MAT_ELEMS : sd;
  __shared__ float t[64][65];
  int bn = blockIdx.x << 6;  // n (out) base
  int bk = blockIdx.y << 6;  // k (in) base
  int tid = threadIdx.x;
  int ln = tid & 63, lk = tid >> 6;
#pragma unroll
  for (int i = 0; i < 16; i++) {
    int k = lk + (i << 2);
    t[k][ln] = src[(size_t)(bk + k) * 1024 + bn + ln];
  }
  __syncthreads();
  int wn = tid >> 4;          // 0..15
  int wk = (tid & 15) << 2;   // 4 bf16 per thread = 8B
  unsigned short* dstm = Wt + (size_t)m * MAT_ELEMS;
#pragma unroll
  for (int j = 0; j < 4; j++) {
    int n = wn + (j << 4);
    uint2 pk;
    pk.x = (unsigned)f2b(t[wk + 0][n]) | ((unsigned)f2b(t[wk + 1][n]) << 16);
    pk.y = (unsigned)f2b(t[wk + 2][n]) | ((unsigned)f2b(t[wk + 3][n]) << 16);
    *(uint2*)&dstm[(size_t)(bn + n) * 1024 + bk + wk] = pk;
  }
}

// ---------- K5: fused gate+up GEMM + silu*up*weight -> bf16 h ----------
// LDS tiles use XOR chunk swizzle: phys_chunk = logical_chunk ^ (row & 7).
// A rows are gathered token-indirect via per-lane global_load_lds addresses.
__global__ __launch_bounds__(256, 3) void gateup_gemm(
    const unsigned short* __restrict__ Xb, const unsigned short* __restrict__ Wt,
    const int* __restrict__ cnt, const int* __restrict__ offs,
    const int* __restrict__ permToken, const float* __restrict__ slotW,
    unsigned short* __restrict__ Hbuf) {
  int e = blockIdx.z;
  int c = cnt[e];
  int m0 = blockIdx.y << 7;
  if (m0 >= c) return;
  int row_base = offs[e] + m0;
  int valid_m = c - m0; if (valid_m > 128) valid_m = 128;
  int n0 = blockIdx.x << 7;

  __shared__ unsigned short sA[128 * 64];
  __shared__ unsigned short sG[128 * 64];
  __shared__ unsigned short sU[128 * 64];

  int tid = threadIdx.x;
  int wv = tid >> 6, lane = tid & 63;
  int wm = wv >> 1, wn = wv & 1;

  const unsigned short* Gg = Wt + (size_t)e * MAT_ELEMS + (size_t)n0 * 1024;
  const unsigned short* Ug = Wt + (size_t)(9 + e) * MAT_ELEMS + (size_t)n0 * 1024;

  int srow = lane >> 3, schunk = lane & 7;
  int swc = (schunk ^ srow) << 3;   // swizzled k-chunk (elements) for staging

  // tokens for the rows this wave stages (gather: no packed-A buffer needed)
  int myTok[4];
#pragma unroll
  for (int j = 0; j < 4; j++)
    myTok[j] = permToken[row_base + (wv << 5) + (j << 3) + srow];

  floatx4 accG[4][4], accU[4][4];
#pragma unroll
  for (int i = 0; i < 4; i++)
#pragma unroll
    for (int j = 0; j < 4; j++) {
      accG[i][j] = floatx4{0.f, 0.f, 0.f, 0.f};
      accU[i][j] = floatx4{0.f, 0.f, 0.f, 0.f};
    }

  for (int kk = 0; kk < 1024; kk += 64) {
    __syncthreads();
#pragma unroll
    for (int j = 0; j < 4; j++) {
      int rb = (wv << 5) + (j << 3);
      size_t gw = (size_t)(rb + srow) * 1024 + kk + swc;
      GLD16(Xb + (size_t)myTok[j] * 1024 + kk + swc, &sA[rb * 64]);
      GLD16(Gg + gw, &sG[rb * 64]);
      GLD16(Ug + gw, &sU[rb * 64]);
    }
    __syncthreads();
#pragma unroll
    for (int k0 = 0; k0 < 64; k0 += 32) {
      int swoff = (((lane >> 4) + (k0 >> 3)) ^ (lane & 7)) << 3;  // same for A & B rows
      int arow = (wm << 6) + (lane & 15);
      short8 af[4];
#pragma unroll
      for (int mi = 0; mi < 4; mi++)
        af[mi] = *(const short8*)&sA[(arow + (mi << 4)) * 64 + swoff];
      int brow = (wn << 6) + (lane & 15);
#pragma unroll
      for (int ni = 0; ni < 4; ni++) {
        short8 gf = *(const short8*)&sG[(brow + (ni << 4)) * 64 + swoff];
        short8 uf = *(const short8*)&sU[(brow + (ni << 4)) * 64 + swoff];
#pragma unroll
        for (int mi = 0; mi < 4; mi++) {
          accG[mi][ni] = __builtin_amdgcn_mfma_f32_16x16x32_bf16(af[mi], gf, accG[mi][ni], 0, 0, 0);
          accU[mi][ni] = __builtin_amdgcn_mfma_f32_16x16x32_bf16(af[mi], uf, accU[mi][ni], 0, 0, 0);
        }
      }
    }
  }

  int colLane = lane & 15, quad = lane >> 4;
#pragma unroll
  for (int mi = 0; mi < 4; mi++) {
#pragma unroll
    for (int reg = 0; reg < 4; reg++) {
      int mrow = (wm << 6) + (mi << 4) + (quad << 2) + reg;
      if (mrow < valid_m) {
        int slot = row_base + mrow;
        float w = slotW[slot];
        unsigned short* hr = Hbuf + (size_t)slot * 1024 + n0 + (wn << 6) + colLane;
#pragma unroll
        for (int ni = 0; ni < 4; ni++) {
          float g = accG[mi][ni][reg];
          float u = accU[mi][ni][reg];
          float h = (g / (1.0f + __expf(-g))) * u * w;
          hr[ni << 4] = f2b(h);
        }
      }
    }
  }
}

// ---------- K6/K7: down projection GEMM; store (shared) or atomicAdd (routed) ----------
template <bool ATOMIC>
__global__ __launch_bounds__(256, 3) void down_gemm(
    const unsigned short* __restrict__ Hbuf, const unsigned short* __restrict__ Wt,
    const int* __restrict__ cnt, const int* __restrict__ offs,
    const int* __restrict__ permToken, float* __restrict__ out, int e_base) {
  int e = e_base + blockIdx.z;
  int c = cnt[e];
  int m0 = blockIdx.y << 7;
  if (m0 >= c) return;
  int row_base = offs[e] + m0;
  int valid_m = c - m0; if (valid_m > 128) valid_m = 128;
  int n0 = blockIdx.x << 7;

  __shared__ unsigned short sA[128 * 64];
  __shared__ unsigned short sB[128 * 64];

  int tid = threadIdx.x;
  int wv = tid >> 6, lane = tid & 63;
  int wm = wv >> 1, wn = wv & 1;

  const unsigned short* Ag = Hbuf + (size_t)row_base * 1024;
  const unsigned short* Bg = Wt + (size_t)(18 + e) * MAT_ELEMS + (size_t)n0 * 1024;

  int srow = lane >> 3, schunk = lane & 7;
  int swc = (schunk ^ srow) << 3;

  floatx4 acc[4][4];
#pragma unroll
  for (int i = 0; i < 4; i++)
#pragma unroll
    for (int j = 0; j < 4; j++) acc[i][j] = floatx4{0.f, 0.f, 0.f, 0.f};

  for (int kk = 0; kk < 1024; kk += 64) {
    __syncthreads();
#pragma unroll
    for (int j = 0; j < 4; j++) {
      int rb = (wv << 5) + (j << 3);
      size_t gw = (size_t)(rb + srow) * 1024 + kk + swc;
      GLD16(Ag + gw, &sA[rb * 64]);
      GLD16(Bg + gw, &sB[rb * 64]);
    }
    __syncthreads();
#pragma unroll
    for (int k0 = 0; k0 < 64; k0 += 32) {
      int swoff = (((lane >> 4) + (k0 >> 3)) ^ (lane & 7)) << 3;
      int arow = (wm << 6) + (lane & 15);
      short8 af[4];
#pragma unroll
      for (int mi = 0; mi < 4; mi++)
        af[mi] = *(const short8*)&sA[(arow + (mi << 4)) * 64 + swoff];
      int brow = (wn << 6) + (lane & 15);
#pragma unroll
      for (int ni = 0; ni < 4; ni++) {
        short8 bf = *(const short8*)&sB[(brow + (ni << 4)) * 64 + swoff];
#pragma unroll
        for (int mi = 0; mi < 4; mi++)
          acc[mi][ni] = __builtin_amdgcn_mfma_f32_16x16x32_bf16(af[mi], bf, acc[mi][ni], 0, 0, 0);
      }
    }
  }

  int colLane = lane & 15, quad = lane >> 4;
#pragma unroll
  for (int mi = 0; mi < 4; mi++) {
#pragma unroll
    for (int reg = 0; reg < 4; reg++) {
      int mrow = (wm << 6) + (mi << 4) + (quad << 2) + reg;
      if (mrow < valid_m) {
        int slot = row_base + mrow;
        int token = permToken[slot];
        float* orow = out + (size_t)token * 1024 + n0 + (wn << 6) + colLane;
#pragma unroll
        for (int ni = 0; ni < 4; ni++) {
          float vvv = acc[mi][ni][reg];
          if (ATOMIC) atomicAdd(&orow[ni << 4], vvv);
          else        orow[ni << 4] = vvv;
        }
      }
    }
  }
}

// ---------- launch ----------
extern "C" void kernel_launch(void* const* d_in, const int* in_sizes, int n_in,
                              void* d_out, int out_size, void* d_ws, size_t ws_size,
                              hipStream_t stream) {
  const float* x  = (const float*)d_in[0];
  const float* sg = (const float*)d_in[1];
  const float* su = (const float*)d_in[2];
  const float* sd = (const float*)d_in[3];
  const float* Wg = (const float*)d_in[4];
  const float* Wu = (const float*)d_in[5];
  const float* Wd = (const float*)d_in[6];
  const float* Wr = (const float*)d_in[7];
  const float* loopTable = (const float*)d_in[8];
  const int*   loopIdx   = (const int*)d_in[9];
  float* out = (float*)d_out;

  char* w = (char*)d_ws;
  unsigned short* Wt = (unsigned short*)w;       w += (size_t)27 * MAT_ELEMS * 2;
  unsigned short* packedX = (unsigned short*)w;  w += (size_t)NSLOT * 1024 * 2;
  unsigned short* Hbuf = (unsigned short*)w;     w += (size_t)NSLOT * 1024 * 2;
  int*   cnt        = (int*)w;   w += 16 * 4;
  int*   offs       = (int*)w;   w += 16 * 4;
  float* bias       = (float*)w; w += 16 * 4;
  int*   permSparse = (int*)w;   w += (size_t)8 * NTOK * 4;
  float* wSparse    = (float*)w; w += (size_t)8 * NTOK * 4;
  int*   permToken  = (int*)w;   w += (size_t)NSLOT * 4;
  float* slotW      = (float*)w; w += (size_t)NSLOT * 4;

  unsigned short* Xb = packedX + (size_t)SHBASE * 1024;  // bf16 cast of x

  setup_kernel<<<1, 256, 0, stream>>>(Wr, loopTable, loopIdx, bias, cnt);
  router_kernel<<<64, 256, 0, stream>>>(x, Wr, bias, packedX, cnt, permSparse,
                                        wSparse, permToken, slotW);
  scan_kernel<<<1, 64, 0, stream>>>(cnt, offs);
  finalize_kernel<<<128, 256, 0, stream>>>(cnt, offs, permSparse, wSparse,
                                           permToken, slotW);
  transpose_cast<<<dim3(16, 16, 27), 256, 0, stream>>>(Wg, Wu, Wd, sg, su, sd, Wt);
  gateup_gemm<<<dim3(8, 32, 9), 256, 0, stream>>>(Xb, Wt, cnt, offs, permToken,
                                                  slotW, Hbuf);
  down_gemm<false><<<dim3(8, 32, 1), 256, 0, stream>>>(Hbuf, Wt, cnt, offs, permToken, out, 8);
  down_gemm<true><<<dim3(8, 32, 8), 256, 0, stream>>>(Hbuf, Wt, cnt, offs, permToken, out, 0);
}

// Round 4
// 324.962 us; speedup vs baseline: 1.2460x; 1.2460x over previous
//
#include <hip/hip_runtime.h>
#include <cstdint>
#include <cstddef>

// ---------- types ----------
typedef __attribute__((ext_vector_type(8))) short short8;   // 8 bf16 = 4 VGPR
typedef __attribute__((ext_vector_type(4))) float floatx4;  // MFMA C/D

#define NTOK   4096
#define NSLOT  12288     // 2*NTOK routed + NTOK shared
#define SHSLOT 8192      // shared slots are always offs[8]=8192..12287 (top-2 exact)
#define MAT_ELEMS (1024 * 1024)

__device__ __forceinline__ unsigned short f2b(float f) {
  unsigned u = __float_as_uint(f);
  u = (u + 0x7fffu + ((u >> 16) & 1u)) >> 16;
  return (unsigned short)u;
}
__device__ __forceinline__ float b2f(unsigned short b) {
  return __uint_as_float((unsigned)b << 16);
}

// async global->LDS, 16B per lane. gsrc: per-lane address, ldst: wave-uniform base.
#define GLD16(gsrc, ldst)                                                              \
  __builtin_amdgcn_global_load_lds(                                                    \
      (const __attribute__((address_space(1))) unsigned int*)(gsrc),                   \
      (__attribute__((address_space(3))) unsigned int*)(ldst), 16, 0, 0)

// ---------- K0: bias from loop embedding, init counters ----------
__global__ void setup_kernel(const float* __restrict__ Wr,
                             const float* __restrict__ loopTable,
                             const int* __restrict__ loopIdx,
                             float* __restrict__ bias, int* __restrict__ cnt) {
  int t = threadIdx.x;
  if (t < 9) cnt[t] = (t == 8) ? NTOK : 0;
  if (t < 8) bias[t] = 0.0f;
  __syncthreads();
  const float* emb = loopTable + (size_t)(*loopIdx) * 1024;
  float partial[8] = {0, 0, 0, 0, 0, 0, 0, 0};
  for (int d = t; d < 1024; d += 256) {
    float ev = emb[d];
    const float* wr = Wr + (size_t)(1024 + d) * 8;
#pragma unroll
    for (int e = 0; e < 8; e++) partial[e] += ev * wr[e];
  }
#pragma unroll
  for (int off = 32; off > 0; off >>= 1)
#pragma unroll
    for (int e = 0; e < 8; e++) partial[e] += __shfl_xor(partial[e], off, 64);
  if ((t & 63) == 0)
#pragma unroll
    for (int e = 0; e < 8; e++) atomicAdd(&bias[e], partial[e]);
}

// ---------- K1: router (64 tokens/block, scalar Wr reads) + x->bf16 cast ----------
__global__ __launch_bounds__(256) void router_kernel(
    const float* __restrict__ x, const float* __restrict__ Wr,
    const float* __restrict__ bias, unsigned short* __restrict__ Xb,
    int* __restrict__ cnt, int* __restrict__ permSparse,
    float* __restrict__ wSparse, int* __restrict__ permToken,
    float* __restrict__ slotW, int2* __restrict__ tokenEPos) {
  int tid = threadIdx.x;
  int lane = tid & 63;
  int seg = __builtin_amdgcn_readfirstlane(tid >> 6);  // wave-uniform
  int tok0 = blockIdx.x << 6;
  int tok = tok0 + lane;

  __shared__ float red[4][64][9];
  __shared__ int lcnt[8];
  __shared__ int lbase[8];
  __shared__ int sE[64][2];
  __shared__ float sP[64][2];
  __shared__ int sPos[64][2];

  if (tid < 8) lcnt[tid] = 0;

  float lg[8] = {0, 0, 0, 0, 0, 0, 0, 0};
  const float* xr = x + (size_t)tok * 1024 + seg * 256;
  const float* wr = Wr + (size_t)seg * 256 * 8;  // scalar base
  for (int i = 0; i < 256; i += 4) {
    float4 xv = *(const float4*)(xr + i);
    float xs[4] = {xv.x, xv.y, xv.z, xv.w};
#pragma unroll
    for (int r = 0; r < 4; r++) {
      const float4* w4 = (const float4*)(wr + (size_t)(i + r) * 8);
      float4 wa = w4[0], wb = w4[1];
      float xv1 = xs[r];
      lg[0] += xv1 * wa.x; lg[1] += xv1 * wa.y; lg[2] += xv1 * wa.z; lg[3] += xv1 * wa.w;
      lg[4] += xv1 * wb.x; lg[5] += xv1 * wb.y; lg[6] += xv1 * wb.z; lg[7] += xv1 * wb.w;
    }
  }
#pragma unroll
  for (int e = 0; e < 8; e++) red[seg][lane][e] = lg[e];
  __syncthreads();

  if (tid < 64) {
    float l[8];
#pragma unroll
    for (int e = 0; e < 8; e++)
      l[e] = red[0][tid][e] + red[1][tid][e] + red[2][tid][e] + red[3][tid][e] + bias[e];
    int i0 = 0; float l0 = l[0];
#pragma unroll
    for (int e = 1; e < 8; e++) if (l[e] > l0) { l0 = l[e]; i0 = e; }
    int i1 = -1; float l1 = -1e30f;
#pragma unroll
    for (int e = 0; e < 8; e++) if (e != i0 && l[e] > l1) { l1 = l[e]; i1 = e; }
    float p0 = 1.0f / (1.0f + __expf(-l0));
    float p1 = 1.0f / (1.0f + __expf(-l1));
    sE[tid][0] = i0; sP[tid][0] = p0; sPos[tid][0] = atomicAdd(&lcnt[i0], 1);
    sE[tid][1] = i1; sP[tid][1] = p1; sPos[tid][1] = atomicAdd(&lcnt[i1], 1);
    int t = tok0 + tid;
    permToken[SHSLOT + t] = t;   // shared slots fixed at 8192+token
    slotW[SHSLOT + t] = 1.0f;
  }
  __syncthreads();
  if (tid < 8) lbase[tid] = atomicAdd(&cnt[tid], lcnt[tid]);
  __syncthreads();
  if (tid < 64) {
    int t = tok0 + tid;
#pragma unroll
    for (int j = 0; j < 2; j++) {
      int e = sE[tid][j];
      int pos = lbase[e] + sPos[tid][j];
      permSparse[e * NTOK + pos] = t;
      wSparse[e * NTOK + pos] = sP[tid][j];
      tokenEPos[t * 2 + j] = make_int2(e, pos);
    }
  }

  // cast 64 token rows -> bf16 (coalesced)
  const float4* xs4 = (const float4*)(x + (size_t)tok0 * 1024);
  uint2* dst = (uint2*)(Xb + (size_t)tok0 * 1024);
  for (int i = tid; i < 64 * 256; i += 256) {
    float4 v = xs4[i];
    uint2 pk;
    pk.x = (unsigned)f2b(v.x) | ((unsigned)f2b(v.y) << 16);
    pk.y = (unsigned)f2b(v.z) | ((unsigned)f2b(v.w) << 16);
    dst[i] = pk;
  }
}

// ---------- K2: exclusive scan of 9 counts ----------
__global__ void scan_kernel(const int* __restrict__ cnt, int* __restrict__ offs) {
  if (threadIdx.x == 0) {
    int s = 0;
    for (int e = 0; e < 9; e++) { offs[e] = s; s += cnt[e]; }
  }
}

// ---------- K3: finalize routed slot metadata ----------
__global__ __launch_bounds__(256) void finalize_kernel(
    const int* __restrict__ cnt, const int* __restrict__ offs,
    const int* __restrict__ permSparse, const float* __restrict__ wSparse,
    int* __restrict__ permToken, float* __restrict__ slotW) {
  int idx = blockIdx.x * 256 + threadIdx.x;   // 8 * NTOK total
  int e = idx >> 12, r = idx & (NTOK - 1);
  if (e < 8 && r < cnt[e]) {
    int slot = offs[e] + r;
    permToken[slot] = permSparse[e * NTOK + r];
    slotW[slot] = wSparse[e * NTOK + r];
  }
}

// ---------- K4: transpose+cast 27 weight matrices to bf16 [out][in] ----------
__global__ __launch_bounds__(256) void transpose_cast(
    const float* __restrict__ Wg, const float* __restrict__ Wu,
    const float* __restrict__ Wd, const float* __restrict__ sg,
    const float* __restrict__ su, const float* __restrict__ sd,
    unsigned short* __restrict__ Wt) {
  int m = blockIdx.z;
  int type = m / 9, e = m % 9;
  const float* src;
  if (type == 0)      src = (e < 8) ? Wg + (size_t)e * MAT_ELEMS : sg;
  else if (type == 1) src = (e < 8) ? Wu + (size_t)e * MAT_ELEMS : su;
  else                src = (e < 8) ? Wd + (size_t)e * MAT_ELEMS : sd;
  __shared__ float t[64][65];
  int bn = blockIdx.x << 6;  // n (out) base
  int bk = blockIdx.y << 6;  // k (in) base
  int tid = threadIdx.x;
  int ln = tid & 63, lk = tid >> 6;
#pragma unroll
  for (int i = 0; i < 16; i++) {
    int k = lk + (i << 2);
    t[k][ln] = src[(size_t)(bk + k) * 1024 + bn + ln];
  }
  __syncthreads();
  int wn = tid >> 4;          // 0..15
  int wk = (tid & 15) << 2;   // 4 bf16 per thread = 8B
  unsigned short* dstm = Wt + (size_t)m * MAT_ELEMS;
#pragma unroll
  for (int j = 0; j < 4; j++) {
    int n = wn + (j << 4);
    uint2 pk;
    pk.x = (unsigned)f2b(t[wk + 0][n]) | ((unsigned)f2b(t[wk + 1][n]) << 16);
    pk.y = (unsigned)f2b(t[wk + 2][n]) | ((unsigned)f2b(t[wk + 3][n]) << 16);
    *(uint2*)&dstm[(size_t)(bn + n) * 1024 + bk + wk] = pk;
  }
}

// ---------- K5: fused gate+up GEMM + silu*up*weight -> bf16 h ----------
// R2 staging (coalesced, unswizzled); A rows gathered token-indirect.
__global__ __launch_bounds__(256, 2) void gateup_gemm(
    const unsigned short* __restrict__ Xb, const unsigned short* __restrict__ Wt,
    const int* __restrict__ cnt, const int* __restrict__ offs,
    const int* __restrict__ permToken, const float* __restrict__ slotW,
    unsigned short* __restrict__ Hbuf) {
  int e = blockIdx.z;
  int c = cnt[e];
  int m0 = blockIdx.y << 7;
  if (m0 >= c) return;
  int row_base = offs[e] + m0;
  int valid_m = c - m0; if (valid_m > 128) valid_m = 128;
  int n0 = blockIdx.x << 7;

  __shared__ unsigned short sA[128 * 64];
  __shared__ unsigned short sG[128 * 64];
  __shared__ unsigned short sU[128 * 64];

  int tid = threadIdx.x;
  int wv = tid >> 6, lane = tid & 63;
  int wm = wv >> 1, wn = wv & 1;

  const unsigned short* Gg = Wt + (size_t)e * MAT_ELEMS + (size_t)n0 * 1024;
  const unsigned short* Ug = Wt + (size_t)(9 + e) * MAT_ELEMS + (size_t)n0 * 1024;

  int srow = lane >> 3, schunk = lane & 7;

  int myTok[4];
#pragma unroll
  for (int j = 0; j < 4; j++)
    myTok[j] = permToken[row_base + (wv << 5) + (j << 3) + srow];

  floatx4 accG[4][4], accU[4][4];
#pragma unroll
  for (int i = 0; i < 4; i++)
#pragma unroll
    for (int j = 0; j < 4; j++) {
      accG[i][j] = floatx4{0.f, 0.f, 0.f, 0.f};
      accU[i][j] = floatx4{0.f, 0.f, 0.f, 0.f};
    }

  for (int kk = 0; kk < 1024; kk += 64) {
    __syncthreads();
#pragma unroll
    for (int j = 0; j < 4; j++) {
      int rb = (wv << 5) + (j << 3);
      size_t gw = (size_t)(rb + srow) * 1024 + kk + (schunk << 3);
      GLD16(Xb + (size_t)myTok[j] * 1024 + kk + (schunk << 3), &sA[rb * 64]);
      GLD16(Gg + gw, &sG[rb * 64]);
      GLD16(Ug + gw, &sU[rb * 64]);
    }
    __syncthreads();
#pragma unroll
    for (int k0 = 0; k0 < 64; k0 += 32) {
      int aoff = ((lane >> 4) << 3) + k0;
      int arow = (wm << 6) + (lane & 15);
      short8 af[4];
#pragma unroll
      for (int mi = 0; mi < 4; mi++)
        af[mi] = *(const short8*)&sA[(arow + (mi << 4)) * 64 + aoff];
      int brow = (wn << 6) + (lane & 15);
#pragma unroll
      for (int ni = 0; ni < 4; ni++) {
        short8 gf = *(const short8*)&sG[(brow + (ni << 4)) * 64 + aoff];
        short8 uf = *(const short8*)&sU[(brow + (ni << 4)) * 64 + aoff];
#pragma unroll
        for (int mi = 0; mi < 4; mi++) {
          accG[mi][ni] = __builtin_amdgcn_mfma_f32_16x16x32_bf16(af[mi], gf, accG[mi][ni], 0, 0, 0);
          accU[mi][ni] = __builtin_amdgcn_mfma_f32_16x16x32_bf16(af[mi], uf, accU[mi][ni], 0, 0, 0);
        }
      }
    }
  }

  int colLane = lane & 15, quad = lane >> 4;
#pragma unroll
  for (int mi = 0; mi < 4; mi++) {
#pragma unroll
    for (int reg = 0; reg < 4; reg++) {
      int mrow = (wm << 6) + (mi << 4) + (quad << 2) + reg;
      if (mrow < valid_m) {
        int slot = row_base + mrow;
        float w = slotW[slot];
        unsigned short* hr = Hbuf + (size_t)slot * 1024 + n0 + (wn << 6) + colLane;
#pragma unroll
        for (int ni = 0; ni < 4; ni++) {
          float g = accG[mi][ni][reg];
          float u = accU[mi][ni][reg];
          float h = (g / (1.0f + __expf(-g))) * u * w;
          hr[ni << 4] = f2b(h);
        }
      }
    }
  }
}

// ---------- K6: down projection GEMM -> bf16 Dbuf[slot] (no atomics) ----------
__global__ __launch_bounds__(256, 2) void down_gemm(
    const unsigned short* __restrict__ Hbuf, const unsigned short* __restrict__ Wt,
    const int* __restrict__ cnt, const int* __restrict__ offs,
    unsigned short* __restrict__ Dbuf) {
  int e = blockIdx.z;
  int c = cnt[e];
  int m0 = blockIdx.y << 7;
  if (m0 >= c) return;
  int row_base = offs[e] + m0;
  int valid_m = c - m0; if (valid_m > 128) valid_m = 128;
  int n0 = blockIdx.x << 7;

  __shared__ unsigned short sA[128 * 64];
  __shared__ unsigned short sB[128 * 64];

  int tid = threadIdx.x;
  int wv = tid >> 6, lane = tid & 63;
  int wm = wv >> 1, wn = wv & 1;

  const unsigned short* Ag = Hbuf + (size_t)row_base * 1024;
  const unsigned short* Bg = Wt + (size_t)(18 + e) * MAT_ELEMS + (size_t)n0 * 1024;

  int srow = lane >> 3, schunk = lane & 7;

  floatx4 acc[4][4];
#pragma unroll
  for (int i = 0; i < 4; i++)
#pragma unroll
    for (int j = 0; j < 4; j++) acc[i][j] = floatx4{0.f, 0.f, 0.f, 0.f};

  for (int kk = 0; kk < 1024; kk += 64) {
    __syncthreads();
#pragma unroll
    for (int j = 0; j < 4; j++) {
      int rb = (wv << 5) + (j << 3);
      size_t gw = (size_t)(rb + srow) * 1024 + kk + (schunk << 3);
      GLD16(Ag + gw, &sA[rb * 64]);
      GLD16(Bg + gw, &sB[rb * 64]);
    }
    __syncthreads();
#pragma unroll
    for (int k0 = 0; k0 < 64; k0 += 32) {
      int aoff = ((lane >> 4) << 3) + k0;
      int arow = (wm << 6) + (lane & 15);
      short8 af[4];
#pragma unroll
      for (int mi = 0; mi < 4; mi++)
        af[mi] = *(const short8*)&sA[(arow + (mi << 4)) * 64 + aoff];
      int brow = (wn << 6) + (lane & 15);
#pragma unroll
      for (int ni = 0; ni < 4; ni++) {
        short8 bf = *(const short8*)&sB[(brow + (ni << 4)) * 64 + aoff];
#pragma unroll
        for (int mi = 0; mi < 4; mi++)
          acc[mi][ni] = __builtin_amdgcn_mfma_f32_16x16x32_bf16(af[mi], bf, acc[mi][ni], 0, 0, 0);
      }
    }
  }

  int colLane = lane & 15, quad = lane >> 4;
#pragma unroll
  for (int mi = 0; mi < 4; mi++) {
#pragma unroll
    for (int reg = 0; reg < 4; reg++) {
      int mrow = (wm << 6) + (mi << 4) + (quad << 2) + reg;
      if (mrow < valid_m) {
        int slot = row_base + mrow;
        unsigned short* dr = Dbuf + (size_t)slot * 1024 + n0 + (wn << 6) + colLane;
#pragma unroll
        for (int ni = 0; ni < 4; ni++)
          dr[ni << 4] = f2b(acc[mi][ni][reg]);
      }
    }
  }
}

// ---------- K7: combine shared + 2 routed rows -> out (fp32) ----------
__global__ __launch_bounds__(256) void combine_kernel(
    const unsigned short* __restrict__ Dbuf, const int* __restrict__ offs,
    const int2* __restrict__ tokenEPos, float* __restrict__ out) {
  int tok = (blockIdx.x << 1) + (threadIdx.x >> 7);
  int lane = threadIdx.x & 127;            // 128 threads/token, 8 elems each
  int2 a = tokenEPos[tok * 2 + 0];
  int2 b = tokenEPos[tok * 2 + 1];
  int s0 = offs[a.x] + a.y;
  int s1 = offs[b.x] + b.y;
  int ssh = SHSLOT + tok;
  int d = lane << 3;
  uint4 r0 = *(const uint4*)(Dbuf + (size_t)ssh * 1024 + d);
  uint4 r1 = *(const uint4*)(Dbuf + (size_t)s0 * 1024 + d);
  uint4 r2 = *(const uint4*)(Dbuf + (size_t)s1 * 1024 + d);
  float o[8];
  const unsigned* u0 = (const unsigned*)&r0;
  const unsigned* u1 = (const unsigned*)&r1;
  const unsigned* u2 = (const unsigned*)&r2;
#pragma unroll
  for (int i = 0; i < 4; i++) {
    o[2 * i + 0] = b2f((unsigned short)(u0[i] & 0xffff)) +
                   b2f((unsigned short)(u1[i] & 0xffff)) +
                   b2f((unsigned short)(u2[i] & 0xffff));
    o[2 * i + 1] = b2f((unsigned short)(u0[i] >> 16)) +
                   b2f((unsigned short)(u1[i] >> 16)) +
                   b2f((unsigned short)(u2[i] >> 16));
  }
  float* orow = out + (size_t)tok * 1024 + d;
  *(float4*)(orow + 0) = make_float4(o[0], o[1], o[2], o[3]);
  *(float4*)(orow + 4) = make_float4(o[4], o[5], o[6], o[7]);
}

// ---------- launch ----------
extern "C" void kernel_launch(void* const* d_in, const int* in_sizes, int n_in,
                              void* d_out, int out_size, void* d_ws, size_t ws_size,
                              hipStream_t stream) {
  const float* x  = (const float*)d_in[0];
  const float* sg = (const float*)d_in[1];
  const float* su = (const float*)d_in[2];
  const float* sd = (const float*)d_in[3];
  const float* Wg = (const float*)d_in[4];
  const float* Wu = (const float*)d_in[5];
  const float* Wd = (const float*)d_in[6];
  const float* Wr = (const float*)d_in[7];
  const float* loopTable = (const float*)d_in[8];
  const int*   loopIdx   = (const int*)d_in[9];
  float* out = (float*)d_out;

  char* w = (char*)d_ws;
  unsigned short* Wt = (unsigned short*)w;    w += (size_t)27 * MAT_ELEMS * 2;
  unsigned short* Xb = (unsigned short*)w;    w += (size_t)NTOK * 1024 * 2;
  unsigned short* Hbuf = (unsigned short*)w;  w += (size_t)NSLOT * 1024 * 2;
  unsigned short* Dbuf = (unsigned short*)w;  w += (size_t)NSLOT * 1024 * 2;
  int*   cnt        = (int*)w;   w += 16 * 4;
  int*   offs       = (int*)w;   w += 16 * 4;
  float* bias       = (float*)w; w += 16 * 4;
  int*   permSparse = (int*)w;   w += (size_t)8 * NTOK * 4;
  float* wSparse    = (float*)w; w += (size_t)8 * NTOK * 4;
  int*   permToken  = (int*)w;   w += (size_t)NSLOT * 4;
  float* slotW      = (float*)w; w += (size_t)NSLOT * 4;
  int2*  tokenEPos  = (int2*)w;  w += (size_t)NTOK * 2 * 8;

  setup_kernel<<<1, 256, 0, stream>>>(Wr, loopTable, loopIdx, bias, cnt);
  router_kernel<<<64, 256, 0, stream>>>(x, Wr, bias, Xb, cnt, permSparse,
                                        wSparse, permToken, slotW, tokenEPos);
  scan_kernel<<<1, 64, 0, stream>>>(cnt, offs);
  finalize_kernel<<<128, 256, 0, stream>>>(cnt, offs, permSparse, wSparse,
                                           permToken, slotW);
  transpose_cast<<<dim3(16, 16, 27), 256, 0, stream>>>(Wg, Wu, Wd, sg, su, sd, Wt);
  gateup_gemm<<<dim3(8, 32, 9), 256, 0, stream>>>(Xb, Wt, cnt, offs, permToken,
                                                  slotW, Hbuf);
  down_gemm<<<dim3(8, 32, 9), 256, 0, stream>>>(Hbuf, Wt, cnt, offs, Dbuf);
  combine_kernel<<<2048, 256, 0, stream>>>(Dbuf, offs, tokenEPos, out);
}

// Round 5
// 311.400 us; speedup vs baseline: 1.3003x; 1.0436x over previous
//
#include <hip/hip_runtime.h>
#include <cstdint>
#include <cstddef>

// ---------- types ----------
typedef __attribute__((ext_vector_type(8))) short short8;   // 8 bf16 = 4 VGPR
typedef __attribute__((ext_vector_type(4))) float floatx4;  // MFMA C/D

#define NTOK   4096
#define NSLOT  12288     // 2*NTOK routed + NTOK shared
#define SHSLOT 8192      // shared slots are always offs[8]=8192..12287 (top-2 exact)
#define MAT_ELEMS (1024 * 1024)

__device__ __forceinline__ unsigned short f2b(float f) {
  unsigned u = __float_as_uint(f);
  u = (u + 0x7fffu + ((u >> 16) & 1u)) >> 16;
  return (unsigned short)u;
}
__device__ __forceinline__ float b2f(unsigned short b) {
  return __uint_as_float((unsigned)b << 16);
}

// async global->LDS, 16B per lane. gsrc: per-lane address, ldst: wave-uniform base.
#define GLD16(gsrc, ldst)                                                              \
  __builtin_amdgcn_global_load_lds(                                                    \
      (const __attribute__((address_space(1))) unsigned int*)(gsrc),                   \
      (__attribute__((address_space(3))) unsigned int*)(ldst), 16, 0, 0)

// ---------- K0: bias from loop embedding, init counters ----------
__global__ void setup_kernel(const float* __restrict__ Wr,
                             const float* __restrict__ loopTable,
                             const int* __restrict__ loopIdx,
                             float* __restrict__ bias, int* __restrict__ cnt) {
  int t = threadIdx.x;
  if (t < 9) cnt[t] = (t == 8) ? NTOK : 0;
  if (t < 8) bias[t] = 0.0f;
  __syncthreads();
  const float* emb = loopTable + (size_t)(*loopIdx) * 1024;
  float partial[8] = {0, 0, 0, 0, 0, 0, 0, 0};
  for (int d = t; d < 1024; d += 256) {
    float ev = emb[d];
    const float* wr = Wr + (size_t)(1024 + d) * 8;
#pragma unroll
    for (int e = 0; e < 8; e++) partial[e] += ev * wr[e];
  }
#pragma unroll
  for (int off = 32; off > 0; off >>= 1)
#pragma unroll
    for (int e = 0; e < 8; e++) partial[e] += __shfl_xor(partial[e], off, 64);
  if ((t & 63) == 0)
#pragma unroll
    for (int e = 0; e < 8; e++) atomicAdd(&bias[e], partial[e]);
}

// ---------- K1: router (64 tokens/block, scalar Wr reads) + x->bf16 cast ----------
__global__ __launch_bounds__(256) void router_kernel(
    const float* __restrict__ x, const float* __restrict__ Wr,
    const float* __restrict__ bias, unsigned short* __restrict__ Xb,
    int* __restrict__ cnt, int* __restrict__ permSparse,
    float* __restrict__ wSparse, int* __restrict__ permToken,
    float* __restrict__ slotW, int2* __restrict__ tokenEPos) {
  int tid = threadIdx.x;
  int lane = tid & 63;
  int seg = __builtin_amdgcn_readfirstlane(tid >> 6);  // wave-uniform
  int tok0 = blockIdx.x << 6;
  int tok = tok0 + lane;

  __shared__ float red[4][64][9];
  __shared__ int lcnt[8];
  __shared__ int lbase[8];
  __shared__ int sE[64][2];
  __shared__ float sP[64][2];
  __shared__ int sPos[64][2];

  if (tid < 8) lcnt[tid] = 0;

  float lg[8] = {0, 0, 0, 0, 0, 0, 0, 0};
  const float* xr = x + (size_t)tok * 1024 + seg * 256;
  const float* wr = Wr + (size_t)seg * 256 * 8;  // scalar base
  for (int i = 0; i < 256; i += 4) {
    float4 xv = *(const float4*)(xr + i);
    float xs[4] = {xv.x, xv.y, xv.z, xv.w};
#pragma unroll
    for (int r = 0; r < 4; r++) {
      const float4* w4 = (const float4*)(wr + (size_t)(i + r) * 8);
      float4 wa = w4[0], wb = w4[1];
      float xv1 = xs[r];
      lg[0] += xv1 * wa.x; lg[1] += xv1 * wa.y; lg[2] += xv1 * wa.z; lg[3] += xv1 * wa.w;
      lg[4] += xv1 * wb.x; lg[5] += xv1 * wb.y; lg[6] += xv1 * wb.z; lg[7] += xv1 * wb.w;
    }
  }
#pragma unroll
  for (int e = 0; e < 8; e++) red[seg][lane][e] = lg[e];
  __syncthreads();

  if (tid < 64) {
    float l[8];
#pragma unroll
    for (int e = 0; e < 8; e++)
      l[e] = red[0][tid][e] + red[1][tid][e] + red[2][tid][e] + red[3][tid][e] + bias[e];
    int i0 = 0; float l0 = l[0];
#pragma unroll
    for (int e = 1; e < 8; e++) if (l[e] > l0) { l0 = l[e]; i0 = e; }
    int i1 = -1; float l1 = -1e30f;
#pragma unroll
    for (int e = 0; e < 8; e++) if (e != i0 && l[e] > l1) { l1 = l[e]; i1 = e; }
    float p0 = 1.0f / (1.0f + __expf(-l0));
    float p1 = 1.0f / (1.0f + __expf(-l1));
    sE[tid][0] = i0; sP[tid][0] = p0; sPos[tid][0] = atomicAdd(&lcnt[i0], 1);
    sE[tid][1] = i1; sP[tid][1] = p1; sPos[tid][1] = atomicAdd(&lcnt[i1], 1);
    int t = tok0 + tid;
    permToken[SHSLOT + t] = t;   // shared slots fixed at 8192+token
    slotW[SHSLOT + t] = 1.0f;
  }
  __syncthreads();
  if (tid < 8) lbase[tid] = atomicAdd(&cnt[tid], lcnt[tid]);
  __syncthreads();
  if (tid < 64) {
    int t = tok0 + tid;
#pragma unroll
    for (int j = 0; j < 2; j++) {
      int e = sE[tid][j];
      int pos = lbase[e] + sPos[tid][j];
      permSparse[e * NTOK + pos] = t;
      wSparse[e * NTOK + pos] = sP[tid][j];
      tokenEPos[t * 2 + j] = make_int2(e, pos);
    }
  }

  // cast 64 token rows -> bf16 (coalesced)
  const float4* xs4 = (const float4*)(x + (size_t)tok0 * 1024);
  uint2* dst = (uint2*)(Xb + (size_t)tok0 * 1024);
  for (int i = tid; i < 64 * 256; i += 256) {
    float4 v = xs4[i];
    uint2 pk;
    pk.x = (unsigned)f2b(v.x) | ((unsigned)f2b(v.y) << 16);
    pk.y = (unsigned)f2b(v.z) | ((unsigned)f2b(v.w) << 16);
    dst[i] = pk;
  }
}

// ---------- K2: exclusive scan of 9 counts ----------
__global__ void scan_kernel(const int* __restrict__ cnt, int* __restrict__ offs) {
  if (threadIdx.x == 0) {
    int s = 0;
    for (int e = 0; e < 9; e++) { offs[e] = s; s += cnt[e]; }
  }
}

// ---------- K3: finalize routed slot metadata ----------
__global__ __launch_bounds__(256) void finalize_kernel(
    const int* __restrict__ cnt, const int* __restrict__ offs,
    const int* __restrict__ permSparse, const float* __restrict__ wSparse,
    int* __restrict__ permToken, float* __restrict__ slotW) {
  int idx = blockIdx.x * 256 + threadIdx.x;   // 8 * NTOK total
  int e = idx >> 12, r = idx & (NTOK - 1);
  if (e < 8 && r < cnt[e]) {
    int slot = offs[e] + r;
    permToken[slot] = permSparse[e * NTOK + r];
    slotW[slot] = wSparse[e * NTOK + r];
  }
}

// ---------- K4: transpose+cast 27 weight matrices to bf16 [out][in] ----------
__global__ __launch_bounds__(256) void transpose_cast(
    const float* __restrict__ Wg, const float* __restrict__ Wu,
    const float* __restrict__ Wd, const float* __restrict__ sg,
    const float* __restrict__ su, const float* __restrict__ sd,
    unsigned short* __restrict__ Wt) {
  int m = blockIdx.z;
  int type = m / 9, e = m % 9;
  const float* src;
  if (type == 0)      src = (e < 8) ? Wg + (size_t)e * MAT_ELEMS : sg;
  else if (type == 1) src = (e < 8) ? Wu + (size_t)e * MAT_ELEMS : su;
  else                src = (e < 8) ? Wd + (size_t)e * MAT_ELEMS : sd;
  __shared__ float t[64][65];
  int bn = blockIdx.x << 6;  // n (out) base
  int bk = blockIdx.y << 6;  // k (in) base
  int tid = threadIdx.x;
  int ln = tid & 63, lk = tid >> 6;
#pragma unroll
  for (int i = 0; i < 16; i++) {
    int k = lk + (i << 2);
    t[k][ln] = src[(size_t)(bk + k) * 1024 + bn + ln];
  }
  __syncthreads();
  int wn = tid >> 4;          // 0..15
  int wk = (tid & 15) << 2;   // 4 bf16 per thread = 8B
  unsigned short* dstm = Wt + (size_t)m * MAT_ELEMS;
#pragma unroll
  for (int j = 0; j < 4; j++) {
    int n = wn + (j << 4);
    uint2 pk;
    pk.x = (unsigned)f2b(t[wk + 0][n]) | ((unsigned)f2b(t[wk + 1][n]) << 16);
    pk.y = (unsigned)f2b(t[wk + 2][n]) | ((unsigned)f2b(t[wk + 3][n]) << 16);
    *(uint2*)&dstm[(size_t)(bn + n) * 1024 + bk + wk] = pk;
  }
}

// ---------- K5: fused gate+up GEMM + silu*up*weight -> bf16 h ----------
// XOR chunk swizzle (phys_chunk = logical ^ (row&7)) with launch_bounds(256,2):
// R3 isolated retry — R3's regression is attributed to VGPR-84 spills
// (WRITE_SIZE +15MB), not the swizzle. Watch WRITE_SIZE stays ~24.6MB.
__global__ __launch_bounds__(256, 2) void gateup_gemm(
    const unsigned short* __restrict__ Xb, const unsigned short* __restrict__ Wt,
    const int* __restrict__ cnt, const int* __restrict__ offs,
    const int* __restrict__ permToken, const float* __restrict__ slotW,
    unsigned short* __restrict__ Hbuf) {
  int e = blockIdx.z;
  int c = cnt[e];
  int m0 = blockIdx.y << 7;
  if (m0 >= c) return;
  int row_base = offs[e] + m0;
  int valid_m = c - m0; if (valid_m > 128) valid_m = 128;
  int n0 = blockIdx.x << 7;

  __shared__ unsigned short sA[128 * 64];
  __shared__ unsigned short sG[128 * 64];
  __shared__ unsigned short sU[128 * 64];

  int tid = threadIdx.x;
  int wv = tid >> 6, lane = tid & 63;
  int wm = wv >> 1, wn = wv & 1;

  const unsigned short* Gg = Wt + (size_t)e * MAT_ELEMS + (size_t)n0 * 1024;
  const unsigned short* Ug = Wt + (size_t)(9 + e) * MAT_ELEMS + (size_t)n0 * 1024;

  int srow = lane >> 3, schunk = lane & 7;
  int swc = (schunk ^ srow) << 3;   // swizzled k-chunk (elements) for staging

  int myTok[4];
#pragma unroll
  for (int j = 0; j < 4; j++)
    myTok[j] = permToken[row_base + (wv << 5) + (j << 3) + srow];

  floatx4 accG[4][4], accU[4][4];
#pragma unroll
  for (int i = 0; i < 4; i++)
#pragma unroll
    for (int j = 0; j < 4; j++) {
      accG[i][j] = floatx4{0.f, 0.f, 0.f, 0.f};
      accU[i][j] = floatx4{0.f, 0.f, 0.f, 0.f};
    }

  for (int kk = 0; kk < 1024; kk += 64) {
    __syncthreads();
#pragma unroll
    for (int j = 0; j < 4; j++) {
      int rb = (wv << 5) + (j << 3);
      size_t gw = (size_t)(rb + srow) * 1024 + kk + swc;
      GLD16(Xb + (size_t)myTok[j] * 1024 + kk + swc, &sA[rb * 64]);
      GLD16(Gg + gw, &sG[rb * 64]);
      GLD16(Ug + gw, &sU[rb * 64]);
    }
    __syncthreads();
#pragma unroll
    for (int k0 = 0; k0 < 64; k0 += 32) {
      int swoff = (((lane >> 4) + (k0 >> 3)) ^ (lane & 7)) << 3;  // logical chunk ^ row&7
      int arow = (wm << 6) + (lane & 15);
      short8 af[4];
#pragma unroll
      for (int mi = 0; mi < 4; mi++)
        af[mi] = *(const short8*)&sA[(arow + (mi << 4)) * 64 + swoff];
      int brow = (wn << 6) + (lane & 15);
#pragma unroll
      for (int ni = 0; ni < 4; ni++) {
        short8 gf = *(const short8*)&sG[(brow + (ni << 4)) * 64 + swoff];
        short8 uf = *(const short8*)&sU[(brow + (ni << 4)) * 64 + swoff];
#pragma unroll
        for (int mi = 0; mi < 4; mi++) {
          accG[mi][ni] = __builtin_amdgcn_mfma_f32_16x16x32_bf16(af[mi], gf, accG[mi][ni], 0, 0, 0);
          accU[mi][ni] = __builtin_amdgcn_mfma_f32_16x16x32_bf16(af[mi], uf, accU[mi][ni], 0, 0, 0);
        }
      }
    }
  }

  int colLane = lane & 15, quad = lane >> 4;
#pragma unroll
  for (int mi = 0; mi < 4; mi++) {
#pragma unroll
    for (int reg = 0; reg < 4; reg++) {
      int mrow = (wm << 6) + (mi << 4) + (quad << 2) + reg;
      if (mrow < valid_m) {
        int slot = row_base + mrow;
        float w = slotW[slot];
        unsigned short* hr = Hbuf + (size_t)slot * 1024 + n0 + (wn << 6) + colLane;
#pragma unroll
        for (int ni = 0; ni < 4; ni++) {
          float g = accG[mi][ni][reg];
          float u = accU[mi][ni][reg];
          float h = (g / (1.0f + __expf(-g))) * u * w;
          hr[ni << 4] = f2b(h);
        }
      }
    }
  }
}

// ---------- K6: down projection GEMM -> bf16 Dbuf[slot] (no atomics) ----------
__global__ __launch_bounds__(256, 2) void down_gemm(
    const unsigned short* __restrict__ Hbuf, const unsigned short* __restrict__ Wt,
    const int* __restrict__ cnt, const int* __restrict__ offs,
    unsigned short* __restrict__ Dbuf) {
  int e = blockIdx.z;
  int c = cnt[e];
  int m0 = blockIdx.y << 7;
  if (m0 >= c) return;
  int row_base = offs[e] + m0;
  int valid_m = c - m0; if (valid_m > 128) valid_m = 128;
  int n0 = blockIdx.x << 7;

  __shared__ unsigned short sA[128 * 64];
  __shared__ unsigned short sB[128 * 64];

  int tid = threadIdx.x;
  int wv = tid >> 6, lane = tid & 63;
  int wm = wv >> 1, wn = wv & 1;

  const unsigned short* Ag = Hbuf + (size_t)row_base * 1024;
  const unsigned short* Bg = Wt + (size_t)(18 + e) * MAT_ELEMS + (size_t)n0 * 1024;

  int srow = lane >> 3, schunk = lane & 7;
  int swc = (schunk ^ srow) << 3;

  floatx4 acc[4][4];
#pragma unroll
  for (int i = 0; i < 4; i++)
#pragma unroll
    for (int j = 0; j < 4; j++) acc[i][j] = floatx4{0.f, 0.f, 0.f, 0.f};

  for (int kk = 0; kk < 1024; kk += 64) {
    __syncthreads();
#pragma unroll
    for (int j = 0; j < 4; j++) {
      int rb = (wv << 5) + (j << 3);
      size_t gw = (size_t)(rb + srow) * 1024 + kk + swc;
      GLD16(Ag + gw, &sA[rb * 64]);
      GLD16(Bg + gw, &sB[rb * 64]);
    }
    __syncthreads();
#pragma unroll
    for (int k0 = 0; k0 < 64; k0 += 32) {
      int swoff = (((lane >> 4) + (k0 >> 3)) ^ (lane & 7)) << 3;
      int arow = (wm << 6) + (lane & 15);
      short8 af[4];
#pragma unroll
      for (int mi = 0; mi < 4; mi++)
        af[mi] = *(const short8*)&sA[(arow + (mi << 4)) * 64 + swoff];
      int brow = (wn << 6) + (lane & 15);
#pragma unroll
      for (int ni = 0; ni < 4; ni++) {
        short8 bf = *(const short8*)&sB[(brow + (ni << 4)) * 64 + swoff];
#pragma unroll
        for (int mi = 0; mi < 4; mi++)
          acc[mi][ni] = __builtin_amdgcn_mfma_f32_16x16x32_bf16(af[mi], bf, acc[mi][ni], 0, 0, 0);
      }
    }
  }

  int colLane = lane & 15, quad = lane >> 4;
#pragma unroll
  for (int mi = 0; mi < 4; mi++) {
#pragma unroll
    for (int reg = 0; reg < 4; reg++) {
      int mrow = (wm << 6) + (mi << 4) + (quad << 2) + reg;
      if (mrow < valid_m) {
        int slot = row_base + mrow;
        unsigned short* dr = Dbuf + (size_t)slot * 1024 + n0 + (wn << 6) + colLane;
#pragma unroll
        for (int ni = 0; ni < 4; ni++)
          dr[ni << 4] = f2b(acc[mi][ni][reg]);
      }
    }
  }
}

// ---------- K7: combine shared + 2 routed rows -> out (fp32) ----------
__global__ __launch_bounds__(256) void combine_kernel(
    const unsigned short* __restrict__ Dbuf, const int* __restrict__ offs,
    const int2* __restrict__ tokenEPos, float* __restrict__ out) {
  int tok = (blockIdx.x << 1) + (threadIdx.x >> 7);
  int lane = threadIdx.x & 127;            // 128 threads/token, 8 elems each
  int2 a = tokenEPos[tok * 2 + 0];
  int2 b = tokenEPos[tok * 2 + 1];
  int s0 = offs[a.x] + a.y;
  int s1 = offs[b.x] + b.y;
  int ssh = SHSLOT + tok;
  int d = lane << 3;
  uint4 r0 = *(const uint4*)(Dbuf + (size_t)ssh * 1024 + d);
  uint4 r1 = *(const uint4*)(Dbuf + (size_t)s0 * 1024 + d);
  uint4 r2 = *(const uint4*)(Dbuf + (size_t)s1 * 1024 + d);
  float o[8];
  const unsigned* u0 = (const unsigned*)&r0;
  const unsigned* u1 = (const unsigned*)&r1;
  const unsigned* u2 = (const unsigned*)&r2;
#pragma unroll
  for (int i = 0; i < 4; i++) {
    o[2 * i + 0] = b2f((unsigned short)(u0[i] & 0xffff)) +
                   b2f((unsigned short)(u1[i] & 0xffff)) +
                   b2f((unsigned short)(u2[i] & 0xffff));
    o[2 * i + 1] = b2f((unsigned short)(u0[i] >> 16)) +
                   b2f((unsigned short)(u1[i] >> 16)) +
                   b2f((unsigned short)(u2[i] >> 16));
  }
  float* orow = out + (size_t)tok * 1024 + d;
  *(float4*)(orow + 0) = make_float4(o[0], o[1], o[2], o[3]);
  *(float4*)(orow + 4) = make_float4(o[4], o[5], o[6], o[7]);
}

// ---------- launch ----------
extern "C" void kernel_launch(void* const* d_in, const int* in_sizes, int n_in,
                              void* d_out, int out_size, void* d_ws, size_t ws_size,
                              hipStream_t stream) {
  const float* x  = (const float*)d_in[0];
  const float* sg = (const float*)d_in[1];
  const float* su = (const float*)d_in[2];
  const float* sd = (const float*)d_in[3];
  const float* Wg = (const float*)d_in[4];
  const float* Wu = (const float*)d_in[5];
  const float* Wd = (const float*)d_in[6];
  const float* Wr = (const float*)d_in[7];
  const float* loopTable = (const float*)d_in[8];
  const int*   loopIdx   = (const int*)d_in[9];
  float* out = (float*)d_out;

  char* w = (char*)d_ws;
  unsigned short* Wt = (unsigned short*)w;    w += (size_t)27 * MAT_ELEMS * 2;
  unsigned short* Xb = (unsigned short*)w;    w += (size_t)NTOK * 1024 * 2;
  unsigned short* Hbuf = (unsigned short*)w;  w += (size_t)NSLOT * 1024 * 2;
  unsigned short* Dbuf = (unsigned short*)w;  w += (size_t)NSLOT * 1024 * 2;
  int*   cnt        = (int*)w;   w += 16 * 4;
  int*   offs       = (int*)w;   w += 16 * 4;
  float* bias       = (float*)w; w += 16 * 4;
  int*   permSparse = (int*)w;   w += (size_t)8 * NTOK * 4;
  float* wSparse    = (float*)w; w += (size_t)8 * NTOK * 4;
  int*   permToken  = (int*)w;   w += (size_t)NSLOT * 4;
  float* slotW      = (float*)w; w += (size_t)NSLOT * 4;
  int2*  tokenEPos  = (int2*)w;  w += (size_t)NTOK * 2 * 8;

  setup_kernel<<<1, 256, 0, stream>>>(Wr, loopTable, loopIdx, bias, cnt);
  router_kernel<<<64, 256, 0, stream>>>(x, Wr, bias, Xb, cnt, permSparse,
                                        wSparse, permToken, slotW, tokenEPos);
  scan_kernel<<<1, 64, 0, stream>>>(cnt, offs);
  finalize_kernel<<<128, 256, 0, stream>>>(cnt, offs, permSparse, wSparse,
                                           permToken, slotW);
  transpose_cast<<<dim3(16, 16, 27), 256, 0, stream>>>(Wg, Wu, Wd, sg, su, sd, Wt);
  gateup_gemm<<<dim3(8, 32, 9), 256, 0, stream>>>(Xb, Wt, cnt, offs, permToken,
                                                  slotW, Hbuf);
  down_gemm<<<dim3(8, 32, 9), 256, 0, stream>>>(Hbuf, Wt, cnt, offs, Dbuf);
  combine_kernel<<<2048, 256, 0, stream>>>(Dbuf, offs, tokenEPos, out);
}

// Round 6
// 306.175 us; speedup vs baseline: 1.3224x; 1.0171x over previous
//
#include <hip/hip_runtime.h>
#include <cstdint>
#include <cstddef>

// ---------- types ----------
typedef __attribute__((ext_vector_type(8))) short short8;   // 8 bf16 = 4 VGPR
typedef __attribute__((ext_vector_type(4))) float floatx4;  // MFMA C/D

#define NTOK   4096
#define NSLOT  12288     // 2*NTOK routed + NTOK shared
#define SHSLOT 8192      // offs[8] == 8192 always (exact top-2)
#define MAT_ELEMS (1024 * 1024)

__device__ __forceinline__ unsigned short f2b(float f) {
  unsigned u = __float_as_uint(f);
  u = (u + 0x7fffu + ((u >> 16) & 1u)) >> 16;
  return (unsigned short)u;
}
__device__ __forceinline__ float b2f(unsigned short b) {
  return __uint_as_float((unsigned)b << 16);
}

// async global->LDS, 16B per lane. gsrc: per-lane address, ldst: wave-uniform base.
#define GLD16(gsrc, ldst)                                                              \
  __builtin_amdgcn_global_load_lds(                                                    \
      (const __attribute__((address_space(1))) unsigned int*)(gsrc),                   \
      (__attribute__((address_space(3))) unsigned int*)(ldst), 16, 0, 0)

// ---------- K1: transpose+cast 27 weight matrices to bf16 [out][in] ----------
// Launched FIRST; block (0,0,0) also zero-inits cnt (stream-serial before router).
__global__ __launch_bounds__(256) void transpose_cast(
    const float* __restrict__ Wg, const float* __restrict__ Wu,
    const float* __restrict__ Wd, const float* __restrict__ sg,
    const float* __restrict__ su, const float* __restrict__ sd,
    unsigned short* __restrict__ Wt, int* __restrict__ cnt) {
  if (blockIdx.x == 0 && blockIdx.y == 0 && blockIdx.z == 0 && threadIdx.x < 9)
    cnt[threadIdx.x] = (threadIdx.x == 8) ? NTOK : 0;
  int m = blockIdx.z;
  int type = m / 9, e = m % 9;
  const float* src;
  if (type == 0)      src = (e < 8) ? Wg + (size_t)e * MAT_ELEMS : sg;
  else if (type == 1) src = (e < 8) ? Wu + (size_t)e * MAT_ELEMS : su;
  else                src = (e < 8) ? Wd + (size_t)e * MAT_ELEMS : sd;
  __shared__ float t[64][65];
  int bn = blockIdx.x << 6;  // n (out) base
  int bk = blockIdx.y << 6;  // k (in) base
  int tid = threadIdx.x;
  int ln = tid & 63, lk = tid >> 6;
#pragma unroll
  for (int i = 0; i < 16; i++) {
    int k = lk + (i << 2);
    t[k][ln] = src[(size_t)(bk + k) * 1024 + bn + ln];
  }
  __syncthreads();
  int wn = tid >> 4;          // 0..15
  int wk = (tid & 15) << 2;   // 4 bf16 per thread = 8B
  unsigned short* dstm = Wt + (size_t)m * MAT_ELEMS;
#pragma unroll
  for (int j = 0; j < 4; j++) {
    int n = wn + (j << 4);
    uint2 pk;
    pk.x = (unsigned)f2b(t[wk + 0][n]) | ((unsigned)f2b(t[wk + 1][n]) << 16);
    pk.y = (unsigned)f2b(t[wk + 2][n]) | ((unsigned)f2b(t[wk + 3][n]) << 16);
    *(uint2*)&dstm[(size_t)(bn + n) * 1024 + bk + wk] = pk;
  }
}

// ---------- K2: router (64 tokens/block) + inline bias + x->bf16 cast ----------
__global__ __launch_bounds__(256) void router_kernel(
    const float* __restrict__ x, const float* __restrict__ Wr,
    const float* __restrict__ loopTable, const int* __restrict__ loopIdx,
    unsigned short* __restrict__ Xb, int* __restrict__ cnt,
    int* __restrict__ permSparse, float* __restrict__ wSparse,
    int2* __restrict__ tokenEPos) {
  int tid = threadIdx.x;
  int lane = tid & 63;
  int seg = __builtin_amdgcn_readfirstlane(tid >> 6);  // wave-uniform
  int tok0 = blockIdx.x << 6;
  int tok = tok0 + lane;

  __shared__ float red[4][64][9];
  __shared__ float sbias[4][8];
  __shared__ int lcnt[8];
  __shared__ int lbase[8];
  __shared__ int sE[64][2];
  __shared__ float sP[64][2];
  __shared__ int sPos[64][2];

  if (tid < 8) lcnt[tid] = 0;

  // inline bias partial: loop_emb @ Wr[1024:2048]
  float bp[8] = {0, 0, 0, 0, 0, 0, 0, 0};
  const float* emb = loopTable + (size_t)(*loopIdx) * 1024;
  for (int d = tid; d < 1024; d += 256) {
    float ev = emb[d];
    const float4* w4 = (const float4*)(Wr + (size_t)(1024 + d) * 8);
    float4 wa = w4[0], wb = w4[1];
    bp[0] += ev * wa.x; bp[1] += ev * wa.y; bp[2] += ev * wa.z; bp[3] += ev * wa.w;
    bp[4] += ev * wb.x; bp[5] += ev * wb.y; bp[6] += ev * wb.z; bp[7] += ev * wb.w;
  }
#pragma unroll
  for (int off = 32; off > 0; off >>= 1)
#pragma unroll
    for (int e = 0; e < 8; e++) bp[e] += __shfl_xor(bp[e], off, 64);
  if (lane == 0)
#pragma unroll
    for (int e = 0; e < 8; e++) sbias[seg][e] = bp[e];

  // logits partial: d in [seg*256, seg*256+256)
  float lg[8] = {0, 0, 0, 0, 0, 0, 0, 0};
  const float* xr = x + (size_t)tok * 1024 + seg * 256;
  const float* wr = Wr + (size_t)seg * 256 * 8;  // scalar base
  for (int i = 0; i < 256; i += 4) {
    float4 xv = *(const float4*)(xr + i);
    float xs[4] = {xv.x, xv.y, xv.z, xv.w};
#pragma unroll
    for (int r = 0; r < 4; r++) {
      const float4* w4 = (const float4*)(wr + (size_t)(i + r) * 8);
      float4 wa = w4[0], wb = w4[1];
      float xv1 = xs[r];
      lg[0] += xv1 * wa.x; lg[1] += xv1 * wa.y; lg[2] += xv1 * wa.z; lg[3] += xv1 * wa.w;
      lg[4] += xv1 * wb.x; lg[5] += xv1 * wb.y; lg[6] += xv1 * wb.z; lg[7] += xv1 * wb.w;
    }
  }
#pragma unroll
  for (int e = 0; e < 8; e++) red[seg][lane][e] = lg[e];
  __syncthreads();

  if (tid < 64) {
    float l[8];
#pragma unroll
    for (int e = 0; e < 8; e++)
      l[e] = red[0][tid][e] + red[1][tid][e] + red[2][tid][e] + red[3][tid][e] +
             sbias[0][e] + sbias[1][e] + sbias[2][e] + sbias[3][e];
    int i0 = 0; float l0 = l[0];
#pragma unroll
    for (int e = 1; e < 8; e++) if (l[e] > l0) { l0 = l[e]; i0 = e; }
    int i1 = -1; float l1 = -1e30f;
#pragma unroll
    for (int e = 0; e < 8; e++) if (e != i0 && l[e] > l1) { l1 = l[e]; i1 = e; }
    float p0 = 1.0f / (1.0f + __expf(-l0));
    float p1 = 1.0f / (1.0f + __expf(-l1));
    sE[tid][0] = i0; sP[tid][0] = p0; sPos[tid][0] = atomicAdd(&lcnt[i0], 1);
    sE[tid][1] = i1; sP[tid][1] = p1; sPos[tid][1] = atomicAdd(&lcnt[i1], 1);
  }
  __syncthreads();
  if (tid < 8) lbase[tid] = atomicAdd(&cnt[tid], lcnt[tid]);
  __syncthreads();
  if (tid < 64) {
    int t = tok0 + tid;
#pragma unroll
    for (int j = 0; j < 2; j++) {
      int e = sE[tid][j];
      int pos = lbase[e] + sPos[tid][j];
      permSparse[e * NTOK + pos] = t;
      wSparse[e * NTOK + pos] = sP[tid][j];
      tokenEPos[t * 2 + j] = make_int2(e, pos);
    }
  }

  // cast 64 token rows -> bf16 (coalesced)
  const float4* xs4 = (const float4*)(x + (size_t)tok0 * 1024);
  uint2* dst = (uint2*)(Xb + (size_t)tok0 * 1024);
  for (int i = tid; i < 64 * 256; i += 256) {
    float4 v = xs4[i];
    uint2 pk;
    pk.x = (unsigned)f2b(v.x) | ((unsigned)f2b(v.y) << 16);
    pk.y = (unsigned)f2b(v.z) | ((unsigned)f2b(v.w) << 16);
    dst[i] = pk;
  }
}

// ---------- K3: fused gate+up GEMM + silu*up*weight -> bf16 h ----------
// XOR chunk swizzle + launch_bounds(256,2) (R5-verified: conflicts 0, no spill).
// Gathers tokens/weights directly from permSparse/wSparse; offs inline from cnt.
__global__ __launch_bounds__(256, 2) void gateup_gemm(
    const unsigned short* __restrict__ Xb, const unsigned short* __restrict__ Wt,
    const int* __restrict__ cnt, const int* __restrict__ permSparse,
    const float* __restrict__ wSparse, unsigned short* __restrict__ Hbuf) {
  int e = blockIdx.z;
  int c = 0, off = 0;
#pragma unroll
  for (int i = 0; i < 9; i++) {
    int cv = cnt[i];
    if (i < e) off += cv;
    if (i == e) c = cv;
  }
  int m0 = blockIdx.y << 7;
  if (m0 >= c) return;
  int row_base = off + m0;
  int valid_m = c - m0; if (valid_m > 128) valid_m = 128;
  int n0 = blockIdx.x << 7;

  __shared__ unsigned short sA[128 * 64];
  __shared__ unsigned short sG[128 * 64];
  __shared__ unsigned short sU[128 * 64];

  int tid = threadIdx.x;
  int wv = tid >> 6, lane = tid & 63;
  int wm = wv >> 1, wn = wv & 1;

  const unsigned short* Gg = Wt + (size_t)e * MAT_ELEMS + (size_t)n0 * 1024;
  const unsigned short* Ug = Wt + (size_t)(9 + e) * MAT_ELEMS + (size_t)n0 * 1024;

  int srow = lane >> 3, schunk = lane & 7;
  int swc = (schunk ^ srow) << 3;   // swizzled k-chunk (elements) for staging

  int myTok[4];
#pragma unroll
  for (int j = 0; j < 4; j++) {
    int r = m0 + (wv << 5) + (j << 3) + srow;
    if (e < 8) myTok[j] = (r < c) ? permSparse[e * NTOK + r] : 0;
    else       myTok[j] = (r < c) ? r : 0;
  }

  floatx4 accG[4][4], accU[4][4];
#pragma unroll
  for (int i = 0; i < 4; i++)
#pragma unroll
    for (int j = 0; j < 4; j++) {
      accG[i][j] = floatx4{0.f, 0.f, 0.f, 0.f};
      accU[i][j] = floatx4{0.f, 0.f, 0.f, 0.f};
    }

  for (int kk = 0; kk < 1024; kk += 64) {
    __syncthreads();
#pragma unroll
    for (int j = 0; j < 4; j++) {
      int rb = (wv << 5) + (j << 3);
      size_t gw = (size_t)(rb + srow) * 1024 + kk + swc;
      GLD16(Xb + (size_t)myTok[j] * 1024 + kk + swc, &sA[rb * 64]);
      GLD16(Gg + gw, &sG[rb * 64]);
      GLD16(Ug + gw, &sU[rb * 64]);
    }
    __syncthreads();
#pragma unroll
    for (int k0 = 0; k0 < 64; k0 += 32) {
      int swoff = (((lane >> 4) + (k0 >> 3)) ^ (lane & 7)) << 3;  // logical chunk ^ row&7
      int arow = (wm << 6) + (lane & 15);
      short8 af[4];
#pragma unroll
      for (int mi = 0; mi < 4; mi++)
        af[mi] = *(const short8*)&sA[(arow + (mi << 4)) * 64 + swoff];
      int brow = (wn << 6) + (lane & 15);
#pragma unroll
      for (int ni = 0; ni < 4; ni++) {
        short8 gf = *(const short8*)&sG[(brow + (ni << 4)) * 64 + swoff];
        short8 uf = *(const short8*)&sU[(brow + (ni << 4)) * 64 + swoff];
#pragma unroll
        for (int mi = 0; mi < 4; mi++) {
          accG[mi][ni] = __builtin_amdgcn_mfma_f32_16x16x32_bf16(af[mi], gf, accG[mi][ni], 0, 0, 0);
          accU[mi][ni] = __builtin_amdgcn_mfma_f32_16x16x32_bf16(af[mi], uf, accU[mi][ni], 0, 0, 0);
        }
      }
    }
  }

  int colLane = lane & 15, quad = lane >> 4;
#pragma unroll
  for (int mi = 0; mi < 4; mi++) {
#pragma unroll
    for (int reg = 0; reg < 4; reg++) {
      int mrow = (wm << 6) + (mi << 4) + (quad << 2) + reg;
      if (mrow < valid_m) {
        int r = m0 + mrow;
        float w = (e < 8) ? wSparse[e * NTOK + r] : 1.0f;
        unsigned short* hr = Hbuf + (size_t)(row_base + mrow) * 1024 + n0 + (wn << 6) + colLane;
#pragma unroll
        for (int ni = 0; ni < 4; ni++) {
          float g = accG[mi][ni][reg];
          float u = accU[mi][ni][reg];
          float h = (g / (1.0f + __expf(-g))) * u * w;
          hr[ni << 4] = f2b(h);
        }
      }
    }
  }
}

// ---------- K4: down projection GEMM -> bf16 Dbuf[slot] (no atomics) ----------
__global__ __launch_bounds__(256, 2) void down_gemm(
    const unsigned short* __restrict__ Hbuf, const unsigned short* __restrict__ Wt,
    const int* __restrict__ cnt, unsigned short* __restrict__ Dbuf) {
  int e = blockIdx.z;
  int c = 0, off = 0;
#pragma unroll
  for (int i = 0; i < 9; i++) {
    int cv = cnt[i];
    if (i < e) off += cv;
    if (i == e) c = cv;
  }
  int m0 = blockIdx.y << 7;
  if (m0 >= c) return;
  int row_base = off + m0;
  int valid_m = c - m0; if (valid_m > 128) valid_m = 128;
  int n0 = blockIdx.x << 7;

  __shared__ unsigned short sA[128 * 64];
  __shared__ unsigned short sB[128 * 64];

  int tid = threadIdx.x;
  int wv = tid >> 6, lane = tid & 63;
  int wm = wv >> 1, wn = wv & 1;

  const unsigned short* Ag = Hbuf + (size_t)row_base * 1024;
  const unsigned short* Bg = Wt + (size_t)(18 + e) * MAT_ELEMS + (size_t)n0 * 1024;

  int srow = lane >> 3, schunk = lane & 7;
  int swc = (schunk ^ srow) << 3;

  floatx4 acc[4][4];
#pragma unroll
  for (int i = 0; i < 4; i++)
#pragma unroll
    for (int j = 0; j < 4; j++) acc[i][j] = floatx4{0.f, 0.f, 0.f, 0.f};

  for (int kk = 0; kk < 1024; kk += 64) {
    __syncthreads();
#pragma unroll
    for (int j = 0; j < 4; j++) {
      int rb = (wv << 5) + (j << 3);
      size_t gw = (size_t)(rb + srow) * 1024 + kk + swc;
      GLD16(Ag + gw, &sA[rb * 64]);
      GLD16(Bg + gw, &sB[rb * 64]);
    }
    __syncthreads();
#pragma unroll
    for (int k0 = 0; k0 < 64; k0 += 32) {
      int swoff = (((lane >> 4) + (k0 >> 3)) ^ (lane & 7)) << 3;
      int arow = (wm << 6) + (lane & 15);
      short8 af[4];
#pragma unroll
      for (int mi = 0; mi < 4; mi++)
        af[mi] = *(const short8*)&sA[(arow + (mi << 4)) * 64 + swoff];
      int brow = (wn << 6) + (lane & 15);
#pragma unroll
      for (int ni = 0; ni < 4; ni++) {
        short8 bf = *(const short8*)&sB[(brow + (ni << 4)) * 64 + swoff];
#pragma unroll
        for (int mi = 0; mi < 4; mi++)
          acc[mi][ni] = __builtin_amdgcn_mfma_f32_16x16x32_bf16(af[mi], bf, acc[mi][ni], 0, 0, 0);
      }
    }
  }

  int colLane = lane & 15, quad = lane >> 4;
#pragma unroll
  for (int mi = 0; mi < 4; mi++) {
#pragma unroll
    for (int reg = 0; reg < 4; reg++) {
      int mrow = (wm << 6) + (mi << 4) + (quad << 2) + reg;
      if (mrow < valid_m) {
        unsigned short* dr = Dbuf + (size_t)(row_base + mrow) * 1024 + n0 + (wn << 6) + colLane;
#pragma unroll
        for (int ni = 0; ni < 4; ni++)
          dr[ni << 4] = f2b(acc[mi][ni][reg]);
      }
    }
  }
}

// ---------- K5: combine shared + 2 routed rows -> out (fp32) ----------
__global__ __launch_bounds__(256) void combine_kernel(
    const unsigned short* __restrict__ Dbuf, const int* __restrict__ cnt,
    const int2* __restrict__ tokenEPos, float* __restrict__ out) {
  __shared__ int soffs[9];
  if (threadIdx.x == 0) {
    int s = 0;
    for (int i = 0; i < 9; i++) { soffs[i] = s; s += cnt[i]; }
  }
  __syncthreads();
  int tok = (blockIdx.x << 1) + (threadIdx.x >> 7);
  int lane = threadIdx.x & 127;            // 128 threads/token, 8 elems each
  int2 a = tokenEPos[tok * 2 + 0];
  int2 b = tokenEPos[tok * 2 + 1];
  int s0 = soffs[a.x] + a.y;
  int s1 = soffs[b.x] + b.y;
  int ssh = SHSLOT + tok;
  int d = lane << 3;
  uint4 r0 = *(const uint4*)(Dbuf + (size_t)ssh * 1024 + d);
  uint4 r1 = *(const uint4*)(Dbuf + (size_t)s0 * 1024 + d);
  uint4 r2 = *(const uint4*)(Dbuf + (size_t)s1 * 1024 + d);
  float o[8];
  const unsigned* u0 = (const unsigned*)&r0;
  const unsigned* u1 = (const unsigned*)&r1;
  const unsigned* u2 = (const unsigned*)&r2;
#pragma unroll
  for (int i = 0; i < 4; i++) {
    o[2 * i + 0] = b2f((unsigned short)(u0[i] & 0xffff)) +
                   b2f((unsigned short)(u1[i] & 0xffff)) +
                   b2f((unsigned short)(u2[i] & 0xffff));
    o[2 * i + 1] = b2f((unsigned short)(u0[i] >> 16)) +
                   b2f((unsigned short)(u1[i] >> 16)) +
                   b2f((unsigned short)(u2[i] >> 16));
  }
  float* orow = out + (size_t)tok * 1024 + d;
  *(float4*)(orow + 0) = make_float4(o[0], o[1], o[2], o[3]);
  *(float4*)(orow + 4) = make_float4(o[4], o[5], o[6], o[7]);
}

// ---------- launch ----------
extern "C" void kernel_launch(void* const* d_in, const int* in_sizes, int n_in,
                              void* d_out, int out_size, void* d_ws, size_t ws_size,
                              hipStream_t stream) {
  const float* x  = (const float*)d_in[0];
  const float* sg = (const float*)d_in[1];
  const float* su = (const float*)d_in[2];
  const float* sd = (const float*)d_in[3];
  const float* Wg = (const float*)d_in[4];
  const float* Wu = (const float*)d_in[5];
  const float* Wd = (const float*)d_in[6];
  const float* Wr = (const float*)d_in[7];
  const float* loopTable = (const float*)d_in[8];
  const int*   loopIdx   = (const int*)d_in[9];
  float* out = (float*)d_out;

  char* w = (char*)d_ws;
  unsigned short* Wt = (unsigned short*)w;    w += (size_t)27 * MAT_ELEMS * 2;
  unsigned short* Xb = (unsigned short*)w;    w += (size_t)NTOK * 1024 * 2;
  unsigned short* Hbuf = (unsigned short*)w;  w += (size_t)NSLOT * 1024 * 2;
  unsigned short* Dbuf = (unsigned short*)w;  w += (size_t)NSLOT * 1024 * 2;
  int*   cnt        = (int*)w;   w += 16 * 4;
  int*   permSparse = (int*)w;   w += (size_t)8 * NTOK * 4;
  float* wSparse    = (float*)w; w += (size_t)8 * NTOK * 4;
  int2*  tokenEPos  = (int2*)w;  w += (size_t)NTOK * 2 * 8;

  // transpose first: zero-inits cnt before router's atomics (stream-serial)
  transpose_cast<<<dim3(16, 16, 27), 256, 0, stream>>>(Wg, Wu, Wd, sg, su, sd, Wt, cnt);
  router_kernel<<<64, 256, 0, stream>>>(x, Wr, loopTable, loopIdx, Xb, cnt,
                                        permSparse, wSparse, tokenEPos);
  gateup_gemm<<<dim3(8, 32, 9), 256, 0, stream>>>(Xb, Wt, cnt, permSparse,
                                                  wSparse, Hbuf);
  down_gemm<<<dim3(8, 32, 9), 256, 0, stream>>>(Hbuf, Wt, cnt, Dbuf);
  combine_kernel<<<2048, 256, 0, stream>>>(Dbuf, cnt, tokenEPos, out);
}

// Round 7
// 304.832 us; speedup vs baseline: 1.3283x; 1.0044x over previous
//
#include <hip/hip_runtime.h>
#include <cstdint>
#include <cstddef>

// ---------- types ----------
typedef __attribute__((ext_vector_type(8))) short short8;   // 8 bf16 = 4 VGPR
typedef __attribute__((ext_vector_type(4))) float floatx4;  // MFMA C/D

#define NTOK   4096
#define NSLOT  12288     // 2*NTOK routed + NTOK shared
#define SHSLOT 8192      // shared-expert rows start here (exact top-2)
#define MAT_ELEMS (1024 * 1024)

__device__ __forceinline__ unsigned short f2b(float f) {
  unsigned u = __float_as_uint(f);
  u = (u + 0x7fffu + ((u >> 16) & 1u)) >> 16;
  return (unsigned short)u;
}
__device__ __forceinline__ float b2f(unsigned short b) {
  return __uint_as_float((unsigned)b << 16);
}

// async global->LDS, 16B per lane. gsrc: per-lane address, ldst: wave-uniform base.
#define GLD16(gsrc, ldst)                                                              \
  __builtin_amdgcn_global_load_lds(                                                    \
      (const __attribute__((address_space(1))) unsigned int*)(gsrc),                   \
      (__attribute__((address_space(3))) unsigned int*)(ldst), 16, 0, 0)

// ---------- K1: router v3 — 256 blocks x 16 tokens (4x CU coverage vs v2) ----------
// Wave seg covers dims [seg*256,+256); lane = token*4 + part, part covers 64 dims.
// Quad shfl-reduce -> LDS cross-wave -> top-2 -> LDS counters -> 8 global atomics.
// Also casts the block's 16 x-rows to bf16 (coalesced).
__global__ __launch_bounds__(256) void router_kernel(
    const float* __restrict__ x, const float* __restrict__ Wr,
    const float* __restrict__ loopTable, const int* __restrict__ loopIdx,
    unsigned short* __restrict__ Xb, int* __restrict__ cnt,
    int* __restrict__ permSparse, float* __restrict__ wSparse,
    int2* __restrict__ tokenEPos) {
  int tid = threadIdx.x;
  int lane = tid & 63;
  int seg = __builtin_amdgcn_readfirstlane(tid >> 6);
  int tok0 = blockIdx.x << 4;
  int t16 = lane >> 2;   // token in block
  int part = lane & 3;   // 64-dim quarter of the wave's 256-dim segment
  int tok = tok0 + t16;

  __shared__ float red[4][16][8];
  __shared__ float sbias[4][8];
  __shared__ int lcnt[8];
  __shared__ int lbase[8];

  if (tid < 8) lcnt[tid] = 0;

  // bias partial: loop_emb @ Wr[1024:]; wave seg covers 256 dims, lane covers 4
  float bp[8] = {0, 0, 0, 0, 0, 0, 0, 0};
  {
    const float* emb = loopTable + (size_t)(*loopIdx) * 1024;
    int d = seg * 256 + lane * 4;
    float4 ev = *(const float4*)(emb + d);
    float es[4] = {ev.x, ev.y, ev.z, ev.w};
#pragma unroll
    for (int r = 0; r < 4; r++) {
      const float4* w4 = (const float4*)(Wr + (size_t)(1024 + d + r) * 8);
      float4 wa = w4[0], wb = w4[1];
      float e1 = es[r];
      bp[0] += e1 * wa.x; bp[1] += e1 * wa.y; bp[2] += e1 * wa.z; bp[3] += e1 * wa.w;
      bp[4] += e1 * wb.x; bp[5] += e1 * wb.y; bp[6] += e1 * wb.z; bp[7] += e1 * wb.w;
    }
  }
#pragma unroll
  for (int off = 32; off > 0; off >>= 1)
#pragma unroll
    for (int e = 0; e < 8; e++) bp[e] += __shfl_xor(bp[e], off, 64);
  if (lane == 0)
#pragma unroll
    for (int e = 0; e < 8; e++) sbias[seg][e] = bp[e];

  // logits partial: lane covers dims seg*256 + part*64 + [0,64)
  float lg[8] = {0, 0, 0, 0, 0, 0, 0, 0};
  const float* xr = x + (size_t)tok * 1024 + seg * 256 + part * 64;
  const float* wrb = Wr + (size_t)(seg * 256 + part * 64) * 8;
  for (int i = 0; i < 64; i += 4) {
    float4 xv = *(const float4*)(xr + i);
    float xs[4] = {xv.x, xv.y, xv.z, xv.w};
#pragma unroll
    for (int r = 0; r < 4; r++) {
      const float4* w4 = (const float4*)(wrb + (size_t)(i + r) * 8);
      float4 wa = w4[0], wb = w4[1];
      float xv1 = xs[r];
      lg[0] += xv1 * wa.x; lg[1] += xv1 * wa.y; lg[2] += xv1 * wa.z; lg[3] += xv1 * wa.w;
      lg[4] += xv1 * wb.x; lg[5] += xv1 * wb.y; lg[6] += xv1 * wb.z; lg[7] += xv1 * wb.w;
    }
  }
  // reduce over the 4 parts (aligned quads)
#pragma unroll
  for (int off = 1; off < 4; off <<= 1)
#pragma unroll
    for (int e = 0; e < 8; e++) lg[e] += __shfl_xor(lg[e], off, 64);
  if (part == 0)
#pragma unroll
    for (int e = 0; e < 8; e++) red[seg][t16][e] = lg[e];
  __syncthreads();

  int i0s = 0, i1s = 0, pos0s = 0, pos1s = 0;
  float p0s = 0.f, p1s = 0.f;
  if (tid < 16) {
    float l[8];
#pragma unroll
    for (int e = 0; e < 8; e++)
      l[e] = red[0][tid][e] + red[1][tid][e] + red[2][tid][e] + red[3][tid][e] +
             sbias[0][e] + sbias[1][e] + sbias[2][e] + sbias[3][e];
    int i0 = 0; float l0 = l[0];
#pragma unroll
    for (int e = 1; e < 8; e++) if (l[e] > l0) { l0 = l[e]; i0 = e; }
    int i1 = -1; float l1 = -1e30f;
#pragma unroll
    for (int e = 0; e < 8; e++) if (e != i0 && l[e] > l1) { l1 = l[e]; i1 = e; }
    i0s = i0; i1s = i1;
    p0s = 1.0f / (1.0f + __expf(-l0));
    p1s = 1.0f / (1.0f + __expf(-l1));
    pos0s = atomicAdd(&lcnt[i0], 1);
    pos1s = atomicAdd(&lcnt[i1], 1);
  }
  __syncthreads();
  if (tid < 8) lbase[tid] = atomicAdd(&cnt[tid], lcnt[tid]);
  __syncthreads();
  if (tid < 16) {
    int t = tok0 + tid;
    int pos0 = lbase[i0s] + pos0s;
    int pos1 = lbase[i1s] + pos1s;
    permSparse[i0s * NTOK + pos0] = t; wSparse[i0s * NTOK + pos0] = p0s;
    permSparse[i1s * NTOK + pos1] = t; wSparse[i1s * NTOK + pos1] = p1s;
    tokenEPos[t * 2 + 0] = make_int2(i0s, pos0);
    tokenEPos[t * 2 + 1] = make_int2(i1s, pos1);
  }

  // cast 16 token rows -> bf16 (coalesced)
  const float4* xs4 = (const float4*)(x + (size_t)tok0 * 1024);
  uint2* dst = (uint2*)(Xb + (size_t)tok0 * 1024);
  for (int i = tid; i < 16 * 256; i += 256) {
    float4 v = xs4[i];
    uint2 pk;
    pk.x = (unsigned)f2b(v.x) | ((unsigned)f2b(v.y) << 16);
    pk.y = (unsigned)f2b(v.z) | ((unsigned)f2b(v.w) << 16);
    dst[i] = pk;
  }
}

// ---------- K2: transpose+cast 27 weight matrices to bf16 [out][in] ----------
// Runs immediately before gateup (R5-verified adjacency: Wt hot in L2/L3).
__global__ __launch_bounds__(256) void transpose_cast(
    const float* __restrict__ Wg, const float* __restrict__ Wu,
    const float* __restrict__ Wd, const float* __restrict__ sg,
    const float* __restrict__ su, const float* __restrict__ sd,
    unsigned short* __restrict__ Wt) {
  int m = blockIdx.z;
  int type = m / 9, e = m % 9;
  const float* src;
  if (type == 0)      src = (e < 8) ? Wg + (size_t)e * MAT_ELEMS : sg;
  else if (type == 1) src = (e < 8) ? Wu + (size_t)e * MAT_ELEMS : su;
  else                src = (e < 8) ? Wd + (size_t)e * MAT_ELEMS : sd;
  __shared__ float t[64][65];
  int bn = blockIdx.x << 6;  // n (out) base
  int bk = blockIdx.y << 6;  // k (in) base
  int tid = threadIdx.x;
  int ln = tid & 63, lk = tid >> 6;
#pragma unroll
  for (int i = 0; i < 16; i++) {
    int k = lk + (i << 2);
    t[k][ln] = src[(size_t)(bk + k) * 1024 + bn + ln];
  }
  __syncthreads();
  int wn = tid >> 4;          // 0..15
  int wk = (tid & 15) << 2;   // 4 bf16 per thread = 8B
  unsigned short* dstm = Wt + (size_t)m * MAT_ELEMS;
#pragma unroll
  for (int j = 0; j < 4; j++) {
    int n = wn + (j << 4);
    uint2 pk;
    pk.x = (unsigned)f2b(t[wk + 0][n]) | ((unsigned)f2b(t[wk + 1][n]) << 16);
    pk.y = (unsigned)f2b(t[wk + 2][n]) | ((unsigned)f2b(t[wk + 3][n]) << 16);
    *(uint2*)&dstm[(size_t)(bn + n) * 1024 + bk + wk] = pk;
  }
}

__device__ __forceinline__ void expert_range(const int* __restrict__ cnt, int e,
                                             int& c, int& off) {
  if (e == 8) { c = NTOK; off = SHSLOT; return; }
  off = 0; c = 0;
#pragma unroll
  for (int i = 0; i < 8; i++) {
    int cv = cnt[i];
    if (i < e) off += cv;
    if (i == e) c = cv;
  }
}

// ---------- K3: fused gate+up GEMM + silu*up*weight -> bf16 h ----------
// XOR chunk swizzle + launch_bounds(256,2) (R5-verified: conflicts 0, no spill).
__global__ __launch_bounds__(256, 2) void gateup_gemm(
    const unsigned short* __restrict__ Xb, const unsigned short* __restrict__ Wt,
    const int* __restrict__ cnt, const int* __restrict__ permSparse,
    const float* __restrict__ wSparse, unsigned short* __restrict__ Hbuf) {
  int e = blockIdx.z;
  int c, off;
  expert_range(cnt, e, c, off);
  int m0 = blockIdx.y << 7;
  if (m0 >= c) return;
  int row_base = off + m0;
  int valid_m = c - m0; if (valid_m > 128) valid_m = 128;
  int n0 = blockIdx.x << 7;

  __shared__ unsigned short sA[128 * 64];
  __shared__ unsigned short sG[128 * 64];
  __shared__ unsigned short sU[128 * 64];

  int tid = threadIdx.x;
  int wv = tid >> 6, lane = tid & 63;
  int wm = wv >> 1, wn = wv & 1;

  const unsigned short* Gg = Wt + (size_t)e * MAT_ELEMS + (size_t)n0 * 1024;
  const unsigned short* Ug = Wt + (size_t)(9 + e) * MAT_ELEMS + (size_t)n0 * 1024;

  int srow = lane >> 3, schunk = lane & 7;
  int swc = (schunk ^ srow) << 3;   // swizzled k-chunk (elements) for staging

  int myTok[4];
#pragma unroll
  for (int j = 0; j < 4; j++) {
    int r = m0 + (wv << 5) + (j << 3) + srow;
    if (e < 8) myTok[j] = (r < c) ? permSparse[e * NTOK + r] : 0;
    else       myTok[j] = (r < c) ? r : 0;
  }

  floatx4 accG[4][4], accU[4][4];
#pragma unroll
  for (int i = 0; i < 4; i++)
#pragma unroll
    for (int j = 0; j < 4; j++) {
      accG[i][j] = floatx4{0.f, 0.f, 0.f, 0.f};
      accU[i][j] = floatx4{0.f, 0.f, 0.f, 0.f};
    }

  for (int kk = 0; kk < 1024; kk += 64) {
    __syncthreads();
#pragma unroll
    for (int j = 0; j < 4; j++) {
      int rb = (wv << 5) + (j << 3);
      size_t gw = (size_t)(rb + srow) * 1024 + kk + swc;
      GLD16(Xb + (size_t)myTok[j] * 1024 + kk + swc, &sA[rb * 64]);
      GLD16(Gg + gw, &sG[rb * 64]);
      GLD16(Ug + gw, &sU[rb * 64]);
    }
    __syncthreads();
#pragma unroll
    for (int k0 = 0; k0 < 64; k0 += 32) {
      int swoff = (((lane >> 4) + (k0 >> 3)) ^ (lane & 7)) << 3;  // logical chunk ^ row&7
      int arow = (wm << 6) + (lane & 15);
      short8 af[4];
#pragma unroll
      for (int mi = 0; mi < 4; mi++)
        af[mi] = *(const short8*)&sA[(arow + (mi << 4)) * 64 + swoff];
      int brow = (wn << 6) + (lane & 15);
#pragma unroll
      for (int ni = 0; ni < 4; ni++) {
        short8 gf = *(const short8*)&sG[(brow + (ni << 4)) * 64 + swoff];
        short8 uf = *(const short8*)&sU[(brow + (ni << 4)) * 64 + swoff];
#pragma unroll
        for (int mi = 0; mi < 4; mi++) {
          accG[mi][ni] = __builtin_amdgcn_mfma_f32_16x16x32_bf16(af[mi], gf, accG[mi][ni], 0, 0, 0);
          accU[mi][ni] = __builtin_amdgcn_mfma_f32_16x16x32_bf16(af[mi], uf, accU[mi][ni], 0, 0, 0);
        }
      }
    }
  }

  int colLane = lane & 15, quad = lane >> 4;
#pragma unroll
  for (int mi = 0; mi < 4; mi++) {
#pragma unroll
    for (int reg = 0; reg < 4; reg++) {
      int mrow = (wm << 6) + (mi << 4) + (quad << 2) + reg;
      if (mrow < valid_m) {
        int r = m0 + mrow;
        float w = (e < 8) ? wSparse[e * NTOK + r] : 1.0f;
        unsigned short* hr = Hbuf + (size_t)(row_base + mrow) * 1024 + n0 + (wn << 6) + colLane;
#pragma unroll
        for (int ni = 0; ni < 4; ni++) {
          float g = accG[mi][ni][reg];
          float u = accU[mi][ni][reg];
          float h = (g / (1.0f + __expf(-g))) * u * w;
          hr[ni << 4] = f2b(h);
        }
      }
    }
  }
}

// ---------- K4: down projection GEMM -> bf16 Dbuf[slot] (no atomics) ----------
__global__ __launch_bounds__(256, 2) void down_gemm(
    const unsigned short* __restrict__ Hbuf, const unsigned short* __restrict__ Wt,
    const int* __restrict__ cnt, unsigned short* __restrict__ Dbuf) {
  int e = blockIdx.z;
  int c, off;
  expert_range(cnt, e, c, off);
  int m0 = blockIdx.y << 7;
  if (m0 >= c) return;
  int row_base = off + m0;
  int valid_m = c - m0; if (valid_m > 128) valid_m = 128;
  int n0 = blockIdx.x << 7;

  __shared__ unsigned short sA[128 * 64];
  __shared__ unsigned short sB[128 * 64];

  int tid = threadIdx.x;
  int wv = tid >> 6, lane = tid & 63;
  int wm = wv >> 1, wn = wv & 1;

  const unsigned short* Ag = Hbuf + (size_t)row_base * 1024;
  const unsigned short* Bg = Wt + (size_t)(18 + e) * MAT_ELEMS + (size_t)n0 * 1024;

  int srow = lane >> 3, schunk = lane & 7;
  int swc = (schunk ^ srow) << 3;

  floatx4 acc[4][4];
#pragma unroll
  for (int i = 0; i < 4; i++)
#pragma unroll
    for (int j = 0; j < 4; j++) acc[i][j] = floatx4{0.f, 0.f, 0.f, 0.f};

  for (int kk = 0; kk < 1024; kk += 64) {
    __syncthreads();
#pragma unroll
    for (int j = 0; j < 4; j++) {
      int rb = (wv << 5) + (j << 3);
      size_t gw = (size_t)(rb + srow) * 1024 + kk + swc;
      GLD16(Ag + gw, &sA[rb * 64]);
      GLD16(Bg + gw, &sB[rb * 64]);
    }
    __syncthreads();
#pragma unroll
    for (int k0 = 0; k0 < 64; k0 += 32) {
      int swoff = (((lane >> 4) + (k0 >> 3)) ^ (lane & 7)) << 3;
      int arow = (wm << 6) + (lane & 15);
      short8 af[4];
#pragma unroll
      for (int mi = 0; mi < 4; mi++)
        af[mi] = *(const short8*)&sA[(arow + (mi << 4)) * 64 + swoff];
      int brow = (wn << 6) + (lane & 15);
#pragma unroll
      for (int ni = 0; ni < 4; ni++) {
        short8 bf = *(const short8*)&sB[(brow + (ni << 4)) * 64 + swoff];
#pragma unroll
        for (int mi = 0; mi < 4; mi++)
          acc[mi][ni] = __builtin_amdgcn_mfma_f32_16x16x32_bf16(af[mi], bf, acc[mi][ni], 0, 0, 0);
      }
    }
  }

  int colLane = lane & 15, quad = lane >> 4;
#pragma unroll
  for (int mi = 0; mi < 4; mi++) {
#pragma unroll
    for (int reg = 0; reg < 4; reg++) {
      int mrow = (wm << 6) + (mi << 4) + (quad << 2) + reg;
      if (mrow < valid_m) {
        unsigned short* dr = Dbuf + (size_t)(row_base + mrow) * 1024 + n0 + (wn << 6) + colLane;
#pragma unroll
        for (int ni = 0; ni < 4; ni++)
          dr[ni << 4] = f2b(acc[mi][ni][reg]);
      }
    }
  }
}

// ---------- K5: combine shared + 2 routed rows -> out (fp32) ----------
__global__ __launch_bounds__(256) void combine_kernel(
    const unsigned short* __restrict__ Dbuf, const int* __restrict__ cnt,
    const int2* __restrict__ tokenEPos, float* __restrict__ out) {
  __shared__ int soffs[8];
  if (threadIdx.x == 0) {
    int s = 0;
    for (int i = 0; i < 8; i++) { soffs[i] = s; s += cnt[i]; }
  }
  __syncthreads();
  int tok = (blockIdx.x << 1) + (threadIdx.x >> 7);
  int lane = threadIdx.x & 127;            // 128 threads/token, 8 elems each
  int2 a = tokenEPos[tok * 2 + 0];
  int2 b = tokenEPos[tok * 2 + 1];
  int s0 = soffs[a.x] + a.y;
  int s1 = soffs[b.x] + b.y;
  int ssh = SHSLOT + tok;
  int d = lane << 3;
  uint4 r0 = *(const uint4*)(Dbuf + (size_t)ssh * 1024 + d);
  uint4 r1 = *(const uint4*)(Dbuf + (size_t)s0 * 1024 + d);
  uint4 r2 = *(const uint4*)(Dbuf + (size_t)s1 * 1024 + d);
  float o[8];
  const unsigned* u0 = (const unsigned*)&r0;
  const unsigned* u1 = (const unsigned*)&r1;
  const unsigned* u2 = (const unsigned*)&r2;
#pragma unroll
  for (int i = 0; i < 4; i++) {
    o[2 * i + 0] = b2f((unsigned short)(u0[i] & 0xffff)) +
                   b2f((unsigned short)(u1[i] & 0xffff)) +
                   b2f((unsigned short)(u2[i] & 0xffff));
    o[2 * i + 1] = b2f((unsigned short)(u0[i] >> 16)) +
                   b2f((unsigned short)(u1[i] >> 16)) +
                   b2f((unsigned short)(u2[i] >> 16));
  }
  float* orow = out + (size_t)tok * 1024 + d;
  *(float4*)(orow + 0) = make_float4(o[0], o[1], o[2], o[3]);
  *(float4*)(orow + 4) = make_float4(o[4], o[5], o[6], o[7]);
}

// ---------- launch ----------
extern "C" void kernel_launch(void* const* d_in, const int* in_sizes, int n_in,
                              void* d_out, int out_size, void* d_ws, size_t ws_size,
                              hipStream_t stream) {
  const float* x  = (const float*)d_in[0];
  const float* sg = (const float*)d_in[1];
  const float* su = (const float*)d_in[2];
  const float* sd = (const float*)d_in[3];
  const float* Wg = (const float*)d_in[4];
  const float* Wu = (const float*)d_in[5];
  const float* Wd = (const float*)d_in[6];
  const float* Wr = (const float*)d_in[7];
  const float* loopTable = (const float*)d_in[8];
  const int*   loopIdx   = (const int*)d_in[9];
  float* out = (float*)d_out;

  char* w = (char*)d_ws;
  unsigned short* Wt = (unsigned short*)w;    w += (size_t)27 * MAT_ELEMS * 2;
  unsigned short* Xb = (unsigned short*)w;    w += (size_t)NTOK * 1024 * 2;
  unsigned short* Hbuf = (unsigned short*)w;  w += (size_t)NSLOT * 1024 * 2;
  unsigned short* Dbuf = (unsigned short*)w;  w += (size_t)NSLOT * 1024 * 2;
  int*   cnt        = (int*)w;   w += 16 * 4;
  int*   permSparse = (int*)w;   w += (size_t)8 * NTOK * 4;
  float* wSparse    = (float*)w; w += (size_t)8 * NTOK * 4;
  int2*  tokenEPos  = (int2*)w;  w += (size_t)NTOK * 2 * 8;

  hipMemsetAsync(cnt, 0, 32, stream);
  router_kernel<<<256, 256, 0, stream>>>(x, Wr, loopTable, loopIdx, Xb, cnt,
                                         permSparse, wSparse, tokenEPos);
  // transpose immediately before gateup: Wt stays hot in L2/L3 (R5 adjacency)
  transpose_cast<<<dim3(16, 16, 27), 256, 0, stream>>>(Wg, Wu, Wd, sg, su, sd, Wt);
  gateup_gemm<<<dim3(8, 32, 9), 256, 0, stream>>>(Xb, Wt, cnt, permSparse,
                                                  wSparse, Hbuf);
  down_gemm<<<dim3(8, 32, 9), 256, 0, stream>>>(Hbuf, Wt, cnt, Dbuf);
  combine_kernel<<<2048, 256, 0, stream>>>(Dbuf, cnt, tokenEPos, out);
}